// Round 20
// baseline (1083.294 us; speedup 1.0000x reference)
//
#include <hip/hip_runtime.h>
#include <hip/hip_bf16.h>

static __device__ __forceinline__ float lrelu(float v){ return v >= 0.f ? v : 0.2f*v; }

#define FMA4(D_, S_, V_) { D_.x += (S_)*(V_).x; D_.y += (S_)*(V_).y; \
                           D_.z += (S_)*(V_).z; D_.w += (S_)*(V_).w; }

// q slots (256 floats):
// 0..2 sum(ea cols) | 3 sum(et2) | 4..6 g1 | 7 c1 | 8..11 g2
// 16..19 vs1 | 20..23 vd1 | 28..35 PM | 36..37 Q
// 40..43 S | 44 s0 | 45..48 D | 49 d0
// 64..127 A=W1@Wm1_top | 128..191 B=W1@Wm1_bot | 192..207 bb

// merged: ea column sums + dst histogram (+ optional rank record)
__global__ void __launch_bounds__(256)
k_hist(const int* __restrict__ ei, const float* __restrict__ ea,
       float* __restrict__ q, unsigned int* __restrict__ cnt,
       unsigned short* __restrict__ rank, int E)
{
    float s0 = 0.f, s1 = 0.f, s2 = 0.f;
    int stride = gridDim.x * blockDim.x;
    for (int e = blockIdx.x*blockDim.x + threadIdx.x; e < E; e += stride){
        size_t o = 3*(size_t)e;
        s0 += ea[o]; s1 += ea[o+1]; s2 += ea[o+2];
        unsigned int r = atomicAdd(&cnt[ei[E + e]], 1u);
        if (rank) rank[e] = (unsigned short)r;
    }
    for (int o = 32; o > 0; o >>= 1){
        s0 += __shfl_down(s0, o);
        s1 += __shfl_down(s1, o);
        s2 += __shfl_down(s2, o);
    }
    if ((threadIdx.x & 63) == 0){
        atomicAdd(&q[0], s0); atomicAdd(&q[1], s1); atomicAdd(&q[2], s2);
    }
}

__global__ void
k_prep(const float* __restrict__ W1, const float* __restrict__ as1,
       const float* __restrict__ ad1,
       const float* __restrict__ We1, const float* __restrict__ ae1,
       const float* __restrict__ b1,
       const float* __restrict__ Wm1, const float* __restrict__ bm1,
       const float* __restrict__ W2, const float* __restrict__ as2,
       const float* __restrict__ ad2,
       const float* __restrict__ We2, const float* __restrict__ ae2,
       float* __restrict__ q, float invE)
{
    __shared__ float sPM[8], sQ[2];
    int t = threadIdx.x;
    if (t < 16){
        int j = t;
        float a0=0,a1=0,a2=0,a3=0, c0=0,c1v=0,c2v=0,c3=0, tb=0;
        for (int i = 0; i < 16; i++){
            float wt = Wm1[i*16 + j];
            float wb = Wm1[(19+i)*16 + j];
            a0 += W1[0*16+i]*wt; a1 += W1[1*16+i]*wt;
            a2 += W1[2*16+i]*wt; a3 += W1[3*16+i]*wt;
            c0 += W1[0*16+i]*wb; c1v += W1[1*16+i]*wb;
            c2v += W1[2*16+i]*wb; c3 += W1[3*16+i]*wb;
            tb += b1[i]*(wt + wb);
        }
        q[64+0*16+j] = a0; q[64+1*16+j] = a1; q[64+2*16+j] = a2; q[64+3*16+j] = a3;
        q[128+0*16+j] = c0; q[128+1*16+j] = c1v; q[128+2*16+j] = c2v; q[128+3*16+j] = c3;
        q[192+j] = bm1[j] + tb;
    } else if (t < 20){
        int c = t - 16;
        float vs = 0.f, vd = 0.f, p0 = 0.f, p1 = 0.f;
        for (int i = 0; i < 16; i++){
            float w = W1[c*16 + i];
            vs += w * as1[i];
            vd += w * ad1[i];
            p0 += w * W2[i*2 + 0];
            p1 += w * W2[i*2 + 1];
        }
        q[16+c] = vs; q[20+c] = vd;
        q[28+c*2+0] = p0; q[28+c*2+1] = p1;
        sPM[c*2+0] = p0; sPM[c*2+1] = p1;
    } else if (t == 20){
        float c1 = 0.f;
        for (int k = 0; k < 3; k++){
            float g = 0.f;
            for (int j = 0; j < 16; j++) g += We1[k*16 + j] * ae1[j];
            q[4+k] = g;
            c1 += q[k] * invE * g;
        }
        q[7] = c1;
    } else if (t == 21){
        for (int k = 0; k < 4; k++)
            q[8+k] = We2[k*2] * ae2[0] + We2[k*2+1] * ae2[1];
    } else if (t == 22){
        float q0 = 0.f, q1 = 0.f;
        for (int i = 0; i < 16; i++){
            q0 += b1[i] * W2[i*2];
            q1 += b1[i] * W2[i*2+1];
        }
        q[36] = q0; q[37] = q1;
        sQ[0] = q0; sQ[1] = q1;
    }
    __syncthreads();
    if (t == 0){
        float a0 = as2[0], a1 = as2[1], d0 = ad2[0], d1 = ad2[1];
        for (int c = 0; c < 4; c++){
            q[40+c] = sPM[c*2]*a0 + sPM[c*2+1]*a1;
            q[45+c] = sPM[c*2]*d0 + sPM[c*2+1]*d1;
        }
        q[44] = sQ[0]*a0 + sQ[1]*a1;
        q[49] = sQ[0]*d0 + sQ[1]*d1;
    }
}

__global__ void __launch_bounds__(256)
k_scan1(const unsigned int* __restrict__ cnt, unsigned int* __restrict__ rowptr,
        unsigned int* __restrict__ aux, int N)
{
    __shared__ unsigned int s[256];
    int t = threadIdx.x;
    int i = blockIdx.x*256 + t;
    unsigned int v = (i < N) ? cnt[i] : 0u;
    s[t] = v;
    __syncthreads();
    for (int off = 1; off < 256; off <<= 1){
        unsigned int add = (t >= off) ? s[t-off] : 0u;
        __syncthreads();
        s[t] += add;
        __syncthreads();
    }
    if (i < N) rowptr[i] = s[t] - v;
    if (t == 255) aux[blockIdx.x] = s[t];
}

__global__ void __launch_bounds__(1024)
k_scan2(unsigned int* __restrict__ aux, int nbs)
{
    __shared__ unsigned int s[1024];
    int t = threadIdx.x;
    unsigned int v = (t < nbs) ? aux[t] : 0u;
    s[t] = v;
    __syncthreads();
    for (int off = 1; off < 1024; off <<= 1){
        unsigned int add = (t >= off) ? s[t-off] : 0u;
        __syncthreads();
        s[t] += add;
        __syncthreads();
    }
    if (t < nbs) aux[t] = s[t] - v;
}

__global__ void __launch_bounds__(256)
k_scan3(unsigned int* __restrict__ rowptr, unsigned int* __restrict__ ofs,
        const unsigned int* __restrict__ aux, int N, int E)
{
    int i = blockIdx.x*256 + threadIdx.x;
    if (i == 0) rowptr[N] = (unsigned int)E;
    if (i >= N) return;
    unsigned int r = rowptr[i] + aux[blockIdx.x];
    rowptr[i] = r;
    ofs[i] = r;   // insert pointers (used only by fallback atomic scatter)
}

__global__ void __launch_bounds__(256)
k_scatter(const int* __restrict__ ei, const float* __restrict__ ea,
          const float* __restrict__ q,
          const unsigned int* __restrict__ rowptr,
          const unsigned short* __restrict__ rank,
          unsigned int* __restrict__ ofs,
          float2* __restrict__ sg, int* __restrict__ posStash, int E)
{
    int e = blockIdx.x*256 + threadIdx.x;
    if (e >= E) return;
    int s = ei[e], d = ei[E + e];
    size_t o = 3*(size_t)e;
    float ge = ea[o]*q[4] + ea[o+1]*q[5] + ea[o+2]*q[6];
    unsigned int pos;
    if (rank){
        pos = rowptr[d] + (unsigned int)rank[e];
    } else {
        pos = atomicAdd(&ofs[d], 1u);
        posStash[4*(size_t)e] = (int)pos;
    }
    float2 r;
    r.x = __int_as_float(s);
    r.y = ge;
    sg[pos] = r;
}

// ---------- layer 1: gather, 2-way unrolled; optional h2 table ----------
__global__ void __launch_bounds__(256)
k_l1(const unsigned int* __restrict__ rowptr,
     const float2* __restrict__ sg, const float* __restrict__ x,
     const float* __restrict__ q, float* __restrict__ xagg,
     float2* __restrict__ h2t, int N)
{
    __shared__ float sq[64];
    if (threadIdx.x < 64) sq[threadIdx.x] = q[threadIdx.x];
    __syncthreads();
    int d = blockIdx.x*256 + threadIdx.x;
    if (d >= N) return;
    float4 xd = ((const float4*)x)[d];
    float hd = xd.x*sq[20] + xd.y*sq[21] + xd.z*sq[22] + xd.w*sq[23];
    float hs_self = xd.x*sq[16] + xd.y*sq[17] + xd.z*sq[18] + xd.w*sq[19];
    float p = expf(fminf(lrelu(hs_self + hd + sq[7]), 60.0f));
    float z0 = p, z1v = 0.f;
    float4 acc0, acc1;
    acc0.x = p*xd.x; acc0.y = p*xd.y; acc0.z = p*xd.z; acc0.w = p*xd.w;
    acc1.x = 0.f; acc1.y = 0.f; acc1.z = 0.f; acc1.w = 0.f;
    unsigned int beg = rowptr[d], end = rowptr[d+1];
    unsigned int j = beg;
    for (; j + 1 < end; j += 2){
        float2 r0 = sg[j];
        float2 r1 = sg[j+1];
        int s0 = __float_as_int(r0.x);
        int s1 = __float_as_int(r1.x);
        float4 xs0 = ((const float4*)x)[s0];
        float4 xs1 = ((const float4*)x)[s1];
        float av0 = xs0.x*sq[16] + xs0.y*sq[17] + xs0.z*sq[18] + xs0.w*sq[19] + hd + r0.y;
        float av1 = xs1.x*sq[16] + xs1.y*sq[17] + xs1.z*sq[18] + xs1.w*sq[19] + hd + r1.y;
        float pv0 = expf(fminf(lrelu(av0), 60.0f));
        float pv1 = expf(fminf(lrelu(av1), 60.0f));
        z0 += pv0; z1v += pv1;
        FMA4(acc0, pv0, xs0);
        FMA4(acc1, pv1, xs1);
    }
    if (j < end){
        float2 r0 = sg[j];
        int s0 = __float_as_int(r0.x);
        float4 xs0 = ((const float4*)x)[s0];
        float av0 = xs0.x*sq[16] + xs0.y*sq[17] + xs0.z*sq[18] + xs0.w*sq[19] + hd + r0.y;
        float pv0 = expf(fminf(lrelu(av0), 60.0f));
        z0 += pv0;
        FMA4(acc0, pv0, xs0);
    }
    float inv = 1.0f / (z0 + z1v);
    float4 acc;
    acc.x = (acc0.x + acc1.x) * inv;
    acc.y = (acc0.y + acc1.y) * inv;
    acc.z = (acc0.z + acc1.z) * inv;
    acc.w = (acc0.w + acc1.w) * inv;
    ((float4*)xagg)[d] = acc;
    if (h2t){
        float2 hh;
        hh.x = acc.x*sq[28] + acc.y*sq[30] + acc.z*sq[32] + acc.w*sq[34] + sq[36];
        hh.y = acc.x*sq[29] + acc.y*sq[31] + acc.z*sq[33] + acc.w*sq[35] + sq[37];
        h2t[d] = hh;
    }
}

// ---------- edge MLP: 4 edges per thread ----------
__global__ void __launch_bounds__(256)
k_mlp(const int* __restrict__ ei, const float* __restrict__ ea,
      const float* __restrict__ xagg,
      const float* __restrict__ Wm1, const float* __restrict__ Wm2,
      const float* __restrict__ bm2, const float* __restrict__ Wm3,
      const float* __restrict__ bm3, const float* __restrict__ Wm4,
      const float* __restrict__ bm4,
      const float* __restrict__ q, float* __restrict__ qw,
      float2* __restrict__ sg,
      const unsigned int* __restrict__ rowptr,
      const unsigned short* __restrict__ rank,
      const int* __restrict__ posStash,
      float* oute, int E)
{
    __shared__ __align__(16) float L[656];
    __shared__ float R[256];
    for (int t = threadIdx.x; t < 656; t += 256){
        float v;
        if      (t < 128)  v = q[64 + t];
        else if (t < 144)  v = q[192 + (t-128)];
        else if (t < 192)  v = Wm1[256 + (t-144)];
        else if (t < 448)  v = Wm2[t-192];
        else if (t < 464)  v = bm2[t-448];
        else if (t < 592)  v = Wm3[t-464];
        else if (t < 600)  v = bm3[t-592];
        else if (t < 632)  v = Wm4[t-600];
        else if (t < 636)  v = bm4[t-632];
        else if (t < 640)  v = q[8 + (t-636)];
        else               v = q[40 + (t-640)];
        L[t] = v;
    }
    __syncthreads();
    const float4* A4  = (const float4*)(L);
    const float4* B4  = (const float4*)(L + 64);
    const float4* bb4 = (const float4*)(L + 128);
    const float4* C34 = (const float4*)(L + 144);
    const float4* W24 = (const float4*)(L + 192);
    const float4* B24 = (const float4*)(L + 448);
    const float4* W34 = (const float4*)(L + 464);
    const float4* B34 = (const float4*)(L + 592);
    const float4* W44 = (const float4*)(L + 600);
    const float*  sg2v = L + 636;
    const float*  SD  = L + 640;

    int tg = blockIdx.x*256 + threadIdx.x;
    int e0 = tg*4;
    float etsum = 0.f;
    if (e0 + 3 < E){
        int4 sis = ((const int4*)ei)[tg];
        int4 dis = ((const int4*)(ei + E))[tg];
        int si[4] = { sis.x, sis.y, sis.z, sis.w };
        int di[4] = { dis.x, dis.y, dis.z, dis.w };
        float4 eA = ((const float4*)ea)[3*tg+0];
        float4 eB = ((const float4*)ea)[3*tg+1];
        float4 eC = ((const float4*)ea)[3*tg+2];
        float eaf[4][3] = {
            { eA.x, eA.y, eA.z },
            { eA.w, eB.x, eB.y },
            { eB.z, eB.w, eC.x },
            { eC.y, eC.z, eC.w }
        };
        int stash[4];
        if (rank){
            ushort4 rr = ((const ushort4*)rank)[tg];
            stash[0] = (int)(rowptr[di[0]] + rr.x);
            stash[1] = (int)(rowptr[di[1]] + rr.y);
            stash[2] = (int)(rowptr[di[2]] + rr.z);
            stash[3] = (int)(rowptr[di[3]] + rr.w);
        } else {
            #pragma unroll
            for (int k = 0; k < 4; k++)
                stash[k] = posStash[4*(size_t)(e0+k)];
        }

        float xsf[4][4], xdf[4][4], hsd[4];
        #pragma unroll
        for (int k = 0; k < 4; k++){
            float4 xs = ((const float4*)xagg)[si[k]];
            float4 xd = ((const float4*)xagg)[di[k]];
            xsf[k][0]=xs.x; xsf[k][1]=xs.y; xsf[k][2]=xs.z; xsf[k][3]=xs.w;
            xdf[k][0]=xd.x; xdf[k][1]=xd.y; xdf[k][2]=xd.z; xdf[k][3]=xd.w;
            float hs2 = xs.x*SD[0] + xs.y*SD[1] + xs.z*SD[2] + xs.w*SD[3] + SD[4];
            float hd2 = xd.x*SD[5] + xd.y*SD[6] + xd.z*SD[7] + xd.w*SD[8] + SD[9];
            hsd[k] = hs2 + hd2;
        }

        float u1[4][16];
        #pragma unroll
        for (int j4 = 0; j4 < 4; j4++){
            float4 acc0 = bb4[j4], acc1 = acc0, acc2 = acc0, acc3 = acc0;
            #pragma unroll
            for (int r = 0; r < 4; r++){
                float4 w = A4[r*4 + j4];
                FMA4(acc0, xsf[0][r], w); FMA4(acc1, xsf[1][r], w);
                FMA4(acc2, xsf[2][r], w); FMA4(acc3, xsf[3][r], w);
            }
            #pragma unroll
            for (int r = 0; r < 3; r++){
                float4 w = C34[r*4 + j4];
                FMA4(acc0, eaf[0][r], w); FMA4(acc1, eaf[1][r], w);
                FMA4(acc2, eaf[2][r], w); FMA4(acc3, eaf[3][r], w);
            }
            #pragma unroll
            for (int r = 0; r < 4; r++){
                float4 w = B4[r*4 + j4];
                FMA4(acc0, xdf[0][r], w); FMA4(acc1, xdf[1][r], w);
                FMA4(acc2, xdf[2][r], w); FMA4(acc3, xdf[3][r], w);
            }
            u1[0][j4*4+0]=fmaxf(acc0.x,0.f); u1[0][j4*4+1]=fmaxf(acc0.y,0.f);
            u1[0][j4*4+2]=fmaxf(acc0.z,0.f); u1[0][j4*4+3]=fmaxf(acc0.w,0.f);
            u1[1][j4*4+0]=fmaxf(acc1.x,0.f); u1[1][j4*4+1]=fmaxf(acc1.y,0.f);
            u1[1][j4*4+2]=fmaxf(acc1.z,0.f); u1[1][j4*4+3]=fmaxf(acc1.w,0.f);
            u1[2][j4*4+0]=fmaxf(acc2.x,0.f); u1[2][j4*4+1]=fmaxf(acc2.y,0.f);
            u1[2][j4*4+2]=fmaxf(acc2.z,0.f); u1[2][j4*4+3]=fmaxf(acc2.w,0.f);
            u1[3][j4*4+0]=fmaxf(acc3.x,0.f); u1[3][j4*4+1]=fmaxf(acc3.y,0.f);
            u1[3][j4*4+2]=fmaxf(acc3.z,0.f); u1[3][j4*4+3]=fmaxf(acc3.w,0.f);
        }

        float u2[4][16];
        #pragma unroll
        for (int j4 = 0; j4 < 4; j4++){
            float4 acc0 = B24[j4], acc1 = acc0, acc2 = acc0, acc3 = acc0;
            #pragma unroll
            for (int c = 0; c < 16; c++){
                float4 w = W24[c*4 + j4];
                FMA4(acc0, u1[0][c], w); FMA4(acc1, u1[1][c], w);
                FMA4(acc2, u1[2][c], w); FMA4(acc3, u1[3][c], w);
            }
            u2[0][j4*4+0]=fmaxf(acc0.x,0.f); u2[0][j4*4+1]=fmaxf(acc0.y,0.f);
            u2[0][j4*4+2]=fmaxf(acc0.z,0.f); u2[0][j4*4+3]=fmaxf(acc0.w,0.f);
            u2[1][j4*4+0]=fmaxf(acc1.x,0.f); u2[1][j4*4+1]=fmaxf(acc1.y,0.f);
            u2[1][j4*4+2]=fmaxf(acc1.z,0.f); u2[1][j4*4+3]=fmaxf(acc1.w,0.f);
            u2[2][j4*4+0]=fmaxf(acc2.x,0.f); u2[2][j4*4+1]=fmaxf(acc2.y,0.f);
            u2[2][j4*4+2]=fmaxf(acc2.z,0.f); u2[2][j4*4+3]=fmaxf(acc2.w,0.f);
            u2[3][j4*4+0]=fmaxf(acc3.x,0.f); u2[3][j4*4+1]=fmaxf(acc3.y,0.f);
            u2[3][j4*4+2]=fmaxf(acc3.z,0.f); u2[3][j4*4+3]=fmaxf(acc3.w,0.f);
        }

        float u3[4][8];
        #pragma unroll
        for (int j2 = 0; j2 < 2; j2++){
            float4 acc0 = B34[j2], acc1 = acc0, acc2 = acc0, acc3 = acc0;
            #pragma unroll
            for (int c = 0; c < 16; c++){
                float4 w = W34[c*2 + j2];
                FMA4(acc0, u2[0][c], w); FMA4(acc1, u2[1][c], w);
                FMA4(acc2, u2[2][c], w); FMA4(acc3, u2[3][c], w);
            }
            u3[0][j2*4+0]=fmaxf(acc0.x,0.f); u3[0][j2*4+1]=fmaxf(acc0.y,0.f);
            u3[0][j2*4+2]=fmaxf(acc0.z,0.f); u3[0][j2*4+3]=fmaxf(acc0.w,0.f);
            u3[1][j2*4+0]=fmaxf(acc1.x,0.f); u3[1][j2*4+1]=fmaxf(acc1.y,0.f);
            u3[1][j2*4+2]=fmaxf(acc1.z,0.f); u3[1][j2*4+3]=fmaxf(acc1.w,0.f);
            u3[2][j2*4+0]=fmaxf(acc2.x,0.f); u3[2][j2*4+1]=fmaxf(acc2.y,0.f);
            u3[2][j2*4+2]=fmaxf(acc2.z,0.f); u3[2][j2*4+3]=fmaxf(acc2.w,0.f);
            u3[3][j2*4+0]=fmaxf(acc3.x,0.f); u3[3][j2*4+1]=fmaxf(acc3.y,0.f);
            u3[3][j2*4+2]=fmaxf(acc3.z,0.f); u3[3][j2*4+3]=fmaxf(acc3.w,0.f);
        }

        float4 ev[4];
        {
            float4 b4v = *(const float4*)(L + 632);
            ev[0] = b4v; ev[1] = b4v; ev[2] = b4v; ev[3] = b4v;
            #pragma unroll
            for (int c = 0; c < 8; c++){
                float4 w = W44[c];
                FMA4(ev[0], u3[0][c], w); FMA4(ev[1], u3[1][c], w);
                FMA4(ev[2], u3[2][c], w); FMA4(ev[3], u3[3][c], w);
            }
        }

        #pragma unroll
        for (int k = 0; k < 4; k++){
            float4 e4 = ev[k];
            float mx = fmaxf(fmaxf(e4.x, e4.y), fmaxf(e4.z, e4.w));
            float ls = logf(expf(e4.x-mx)+expf(e4.y-mx)+expf(e4.z-mx)+expf(e4.w-mx)) + mx;
            float4 o;
            o.x = e4.x-ls; o.y = e4.y-ls; o.z = e4.z-ls; o.w = e4.w-ls;
            ((float4*)oute)[e0+k] = o;
            float et = e4.x*sg2v[0] + e4.y*sg2v[1] + e4.z*sg2v[2] + e4.w*sg2v[3];
            etsum += et;
            sg[stash[k]].y = lrelu(hsd[k] + et);
        }
    } else if (e0 < E){
        for (int e = e0; e < E; e++){
            int sp;
            if (rank) sp = (int)(rowptr[ei[E+e]] + rank[e]);
            else      sp = posStash[4*(size_t)e];
            int si = ei[e], di = ei[E+e];
            float4 xs = ((const float4*)xagg)[si];
            float4 xd = ((const float4*)xagg)[di];
            size_t eo = 3*(size_t)e;
            float e0v = ea[eo], e1v = ea[eo+1], e2v = ea[eo+2];
            float u1s[16];
            #pragma unroll
            for (int j4 = 0; j4 < 4; j4++){
                float4 acc = bb4[j4];
                FMA4(acc, xs.x, A4[0*4+j4]); FMA4(acc, xs.y, A4[1*4+j4]);
                FMA4(acc, xs.z, A4[2*4+j4]); FMA4(acc, xs.w, A4[3*4+j4]);
                FMA4(acc, e0v, C34[0*4+j4]); FMA4(acc, e1v, C34[1*4+j4]);
                FMA4(acc, e2v, C34[2*4+j4]);
                FMA4(acc, xd.x, B4[0*4+j4]); FMA4(acc, xd.y, B4[1*4+j4]);
                FMA4(acc, xd.z, B4[2*4+j4]); FMA4(acc, xd.w, B4[3*4+j4]);
                u1s[j4*4+0]=fmaxf(acc.x,0.f); u1s[j4*4+1]=fmaxf(acc.y,0.f);
                u1s[j4*4+2]=fmaxf(acc.z,0.f); u1s[j4*4+3]=fmaxf(acc.w,0.f);
            }
            float u2s[16];
            #pragma unroll
            for (int j4 = 0; j4 < 4; j4++){
                float4 acc = B24[j4];
                #pragma unroll
                for (int c = 0; c < 16; c++) FMA4(acc, u1s[c], W24[c*4+j4]);
                u2s[j4*4+0]=fmaxf(acc.x,0.f); u2s[j4*4+1]=fmaxf(acc.y,0.f);
                u2s[j4*4+2]=fmaxf(acc.z,0.f); u2s[j4*4+3]=fmaxf(acc.w,0.f);
            }
            float u3s[8];
            #pragma unroll
            for (int j2 = 0; j2 < 2; j2++){
                float4 acc = B34[j2];
                #pragma unroll
                for (int c = 0; c < 16; c++) FMA4(acc, u2s[c], W34[c*2+j2]);
                u3s[j2*4+0]=fmaxf(acc.x,0.f); u3s[j2*4+1]=fmaxf(acc.y,0.f);
                u3s[j2*4+2]=fmaxf(acc.z,0.f); u3s[j2*4+3]=fmaxf(acc.w,0.f);
            }
            float4 e4 = *(const float4*)(L + 632);
            #pragma unroll
            for (int c = 0; c < 8; c++) FMA4(e4, u3s[c], W44[c]);
            float mx = fmaxf(fmaxf(e4.x, e4.y), fmaxf(e4.z, e4.w));
            float ls = logf(expf(e4.x-mx)+expf(e4.y-mx)+expf(e4.z-mx)+expf(e4.w-mx)) + mx;
            float4 o;
            o.x = e4.x-ls; o.y = e4.y-ls; o.z = e4.z-ls; o.w = e4.w-ls;
            ((float4*)oute)[e] = o;
            float et = e4.x*sg2v[0] + e4.y*sg2v[1] + e4.z*sg2v[2] + e4.w*sg2v[3];
            etsum += et;
            float hs2 = xs.x*SD[0] + xs.y*SD[1] + xs.z*SD[2] + xs.w*SD[3] + SD[4];
            float hd2 = xd.x*SD[5] + xd.y*SD[6] + xd.z*SD[7] + xd.w*SD[8] + SD[9];
            sg[sp].y = lrelu(hs2 + hd2 + et);
        }
    }
    R[threadIdx.x] = etsum;
    __syncthreads();
    for (int off = 128; off > 0; off >>= 1){
        if (threadIdx.x < off) R[threadIdx.x] += R[threadIdx.x + off];
        __syncthreads();
    }
    if (threadIdx.x == 0) atomicAdd(&qw[3], R[0]);
}

// ---------- layer 2: single-pass online softmax, fused output ----------
__global__ void __launch_bounds__(256)
k_l2(const unsigned int* __restrict__ rowptr,
     const float2* __restrict__ sg, const float* __restrict__ xagg,
     const float2* __restrict__ h2t,
     const float* __restrict__ q, const float* __restrict__ b2,
     float* __restrict__ outn, float invE, int N)
{
    __shared__ float sq[64];
    if (threadIdx.x < 64) sq[threadIdx.x] = q[threadIdx.x];
    __syncthreads();
    int d = blockIdx.x*256 + threadIdx.x;
    if (d >= N) return;
    float c2 = sq[3] * invE;
    float4 xa = ((const float4*)xagg)[d];
    float h2d0 = xa.x*sq[28] + xa.y*sq[30] + xa.z*sq[32] + xa.w*sq[34] + sq[36];
    float h2d1 = xa.x*sq[29] + xa.y*sq[31] + xa.z*sq[33] + xa.w*sq[35] + sq[37];
    float hs2 = xa.x*sq[40] + xa.y*sq[41] + xa.z*sq[42] + xa.w*sq[43] + sq[44];
    float hd2 = xa.x*sq[45] + xa.y*sq[46] + xa.z*sq[47] + xa.w*sq[48] + sq[49];
    float aself = lrelu(hs2 + hd2 + c2);

    float mA = aself, zA = 1.f, a0A = h2d0, a1A = h2d1;
    float mB = -1e30f, zB = 0.f, a0B = 0.f, a1B = 0.f;

    unsigned int beg = rowptr[d], end = rowptr[d+1];
    unsigned int j = beg;
    for (; j + 1 < end; j += 2){
        float2 r0 = sg[j];
        float2 r1 = sg[j+1];
        int s0 = __float_as_int(r0.x);
        int s1 = __float_as_int(r1.x);
        float h00, h01, h10, h11;
        if (h2t){
            float2 hh0 = h2t[s0];
            float2 hh1 = h2t[s1];
            h00 = hh0.x; h01 = hh0.y; h10 = hh1.x; h11 = hh1.y;
        } else {
            float4 xs0 = ((const float4*)xagg)[s0];
            float4 xs1 = ((const float4*)xagg)[s1];
            h00 = xs0.x*sq[28] + xs0.y*sq[30] + xs0.z*sq[32] + xs0.w*sq[34] + sq[36];
            h01 = xs0.x*sq[29] + xs0.y*sq[31] + xs0.z*sq[33] + xs0.w*sq[35] + sq[37];
            h10 = xs1.x*sq[28] + xs1.y*sq[30] + xs1.z*sq[32] + xs1.w*sq[34] + sq[36];
            h11 = xs1.x*sq[29] + xs1.y*sq[31] + xs1.z*sq[33] + xs1.w*sq[35] + sq[37];
        }
        float mn0 = fmaxf(mA, r0.y);
        float sc0 = expf(mA - mn0);
        float p0  = expf(r0.y - mn0);
        zA  = zA*sc0 + p0;
        a0A = a0A*sc0 + p0*h00;
        a1A = a1A*sc0 + p0*h01;
        mA = mn0;
        float mn1 = fmaxf(mB, r1.y);
        float sc1 = expf(mB - mn1);
        float p1  = expf(r1.y - mn1);
        zB  = zB*sc1 + p1;
        a0B = a0B*sc1 + p1*h10;
        a1B = a1B*sc1 + p1*h11;
        mB = mn1;
    }
    if (j < end){
        float2 r0 = sg[j];
        int s0 = __float_as_int(r0.x);
        float h00, h01;
        if (h2t){
            float2 hh0 = h2t[s0];
            h00 = hh0.x; h01 = hh0.y;
        } else {
            float4 xs0 = ((const float4*)xagg)[s0];
            h00 = xs0.x*sq[28] + xs0.y*sq[30] + xs0.z*sq[32] + xs0.w*sq[34] + sq[36];
            h01 = xs0.x*sq[29] + xs0.y*sq[31] + xs0.z*sq[33] + xs0.w*sq[35] + sq[37];
        }
        float mn0 = fmaxf(mA, r0.y);
        float sc0 = expf(mA - mn0);
        float p0  = expf(r0.y - mn0);
        zA  = zA*sc0 + p0;
        a0A = a0A*sc0 + p0*h00;
        a1A = a1A*sc0 + p0*h01;
        mA = mn0;
    }
    float m = fmaxf(mA, mB);
    float sA = expf(mA - m), sB = expf(mB - m);
    float z = zA*sA + zB*sB;
    float inv = 1.0f / z;
    float v0 = (a0A*sA + a0B*sB)*inv + b2[0];
    float v1 = (a1A*sA + a1B*sB)*inv + b2[1];
    float mm = fmaxf(v0, v1);
    float ls = logf(expf(v0-mm) + expf(v1-mm)) + mm;
    float2 o;
    o.x = v0 - ls;
    o.y = v1 - ls;
    ((float2*)outn)[d] = o;
}

extern "C" void kernel_launch(void* const* d_in, const int* in_sizes, int n_in,
                              void* d_out, int out_size, void* d_ws, size_t ws_size,
                              hipStream_t stream)
{
    const float* x   = (const float*)d_in[0];
    const int*   ei  = (const int*)  d_in[1];
    const float* ea  = (const float*)d_in[2];
    const float* W1  = (const float*)d_in[3];
    const float* as1 = (const float*)d_in[4];
    const float* ad1 = (const float*)d_in[5];
    const float* We1 = (const float*)d_in[6];
    const float* ae1 = (const float*)d_in[7];
    const float* b1  = (const float*)d_in[8];
    const float* Wm1 = (const float*)d_in[9];
    const float* bm1 = (const float*)d_in[10];
    const float* Wm2 = (const float*)d_in[11];
    const float* bm2 = (const float*)d_in[12];
    const float* Wm3 = (const float*)d_in[13];
    const float* bm3 = (const float*)d_in[14];
    const float* Wm4 = (const float*)d_in[15];
    const float* bm4 = (const float*)d_in[16];
    const float* W2  = (const float*)d_in[17];
    const float* as2 = (const float*)d_in[18];
    const float* ad2 = (const float*)d_in[19];
    const float* We2 = (const float*)d_in[20];
    const float* ae2 = (const float*)d_in[21];
    const float* b2  = (const float*)d_in[22];

    const int N = in_sizes[0] / 4;
    const int E = in_sizes[1] / 2;

    int nb_n = (N + 255) / 256;
    int nb_e = (E + 255) / 256;
    int nb_e4 = (E + 1023) / 1024;
    if (nb_n > 1024) return;

    // common: q(256) | cnt(N u32) | rowptr(N+64 u32) | aux(1024 u32) | xagg(4N) | sg(2E)
    size_t commonFloats = 256 + (size_t)N + ((size_t)N + 64) + 1024 + 4*(size_t)N + 2*(size_t)E;
    // upgraded: + h2t(2N) + rank(E u16 -> E/2+16 floats)
    size_t upFloats = commonFloats + 2*(size_t)N + ((size_t)E/2 + 16);
    if (ws_size < commonFloats*sizeof(float)) return;
    bool up = (ws_size >= upFloats*sizeof(float));

    float* ws = (float*)d_ws;
    float* q  = ws;
    unsigned int* cnt    = (unsigned int*)(ws + 256);
    unsigned int* rowptr = cnt + N;
    unsigned int* aux    = rowptr + N + 64;
    float* xagg = (float*)(aux + 1024);
    float2* sg  = (float2*)(xagg + 4*(size_t)N);
    float2* h2t = nullptr;
    unsigned short* rank = nullptr;
    if (up){
        h2t  = (float2*)(sg + (size_t)E);
        rank = (unsigned short*)(h2t + (size_t)N);
    }

    float* outn = (float*)d_out;
    float* oute = outn + 2*(size_t)N;
    int* posStash = (int*)oute;   // fallback stash (each edge's own oute slot)

    // zero q + cnt
    hipMemsetAsync(d_ws, 0, (256 + (size_t)N)*sizeof(float), stream);

    float invE = 1.0f / (float)E;

    k_hist<<<4096,256,0,stream>>>(ei, ea, q, cnt, rank, E);
    k_prep<<<1,64,0,stream>>>(W1, as1, ad1, We1, ae1, b1, Wm1, bm1,
                              W2, as2, ad2, We2, ae2, q, invE);
    k_scan1<<<nb_n,256,0,stream>>>(cnt, rowptr, aux, N);
    k_scan2<<<1,1024,0,stream>>>(aux, nb_n);
    k_scan3<<<nb_n,256,0,stream>>>(rowptr, cnt, aux, N, E);   // cnt becomes insert ptrs (fallback)
    k_scatter<<<nb_e,256,0,stream>>>(ei, ea, q, rowptr, rank, cnt, sg, posStash, E);
    k_l1<<<nb_n,256,0,stream>>>(rowptr, sg, x, q, xagg, h2t, N);
    k_mlp<<<nb_e4,256,0,stream>>>(ei, ea, xagg, Wm1, Wm2, bm2, Wm3, bm3,
                                  Wm4, bm4, q, q, sg, rowptr, rank, posStash, oute, E);
    k_l2<<<nb_n,256,0,stream>>>(rowptr, sg, xagg, h2t, q, b2, outn, invE, N);
}

// Round 21
// 591.584 us; speedup vs baseline: 1.8312x; 1.8312x over previous
//
#include <hip/hip_runtime.h>
#include <hip/hip_bf16.h>

static __device__ __forceinline__ float lrelu(float v){ return v >= 0.f ? v : 0.2f*v; }

#define FMA4(D_, S_, V_) { D_.x += (S_)*(V_).x; D_.y += (S_)*(V_).y; \
                           D_.z += (S_)*(V_).z; D_.w += (S_)*(V_).w; }

// q slots (256 floats):
// 0..2 sum(ea cols) | 3 sum(et2) | 4..6 g1 | 7 c1 | 8..11 g2
// 16..19 vs1 | 20..23 vd1 | 28..35 PM | 36..37 Q
// 40..43 S | 44 s0 | 45..48 D | 49 d0
// 64..127 A=W1@Wm1_top | 128..191 B=W1@Wm1_bot | 192..207 bb

// merged: ea column sums + dst histogram (+ optional rank record)
__global__ void __launch_bounds__(256)
k_hist(const int* __restrict__ ei, const float* __restrict__ ea,
       float* __restrict__ q, unsigned int* __restrict__ cnt,
       unsigned short* __restrict__ rank, int E)
{
    float s0 = 0.f, s1 = 0.f, s2 = 0.f;
    int stride = gridDim.x * blockDim.x;
    for (int e = blockIdx.x*blockDim.x + threadIdx.x; e < E; e += stride){
        size_t o = 3*(size_t)e;
        s0 += ea[o]; s1 += ea[o+1]; s2 += ea[o+2];
        unsigned int r = atomicAdd(&cnt[ei[E + e]], 1u);
        if (rank) rank[e] = (unsigned short)r;
    }
    for (int o = 32; o > 0; o >>= 1){
        s0 += __shfl_down(s0, o);
        s1 += __shfl_down(s1, o);
        s2 += __shfl_down(s2, o);
    }
    if ((threadIdx.x & 63) == 0){
        atomicAdd(&q[0], s0); atomicAdd(&q[1], s1); atomicAdd(&q[2], s2);
    }
}

__global__ void
k_prep(const float* __restrict__ W1, const float* __restrict__ as1,
       const float* __restrict__ ad1,
       const float* __restrict__ We1, const float* __restrict__ ae1,
       const float* __restrict__ b1,
       const float* __restrict__ Wm1, const float* __restrict__ bm1,
       const float* __restrict__ W2, const float* __restrict__ as2,
       const float* __restrict__ ad2,
       const float* __restrict__ We2, const float* __restrict__ ae2,
       float* __restrict__ q, float invE)
{
    __shared__ float sPM[8], sQ[2];
    int t = threadIdx.x;
    if (t < 16){
        int j = t;
        float a0=0,a1=0,a2=0,a3=0, c0=0,c1v=0,c2v=0,c3=0, tb=0;
        for (int i = 0; i < 16; i++){
            float wt = Wm1[i*16 + j];
            float wb = Wm1[(19+i)*16 + j];
            a0 += W1[0*16+i]*wt; a1 += W1[1*16+i]*wt;
            a2 += W1[2*16+i]*wt; a3 += W1[3*16+i]*wt;
            c0 += W1[0*16+i]*wb; c1v += W1[1*16+i]*wb;
            c2v += W1[2*16+i]*wb; c3 += W1[3*16+i]*wb;
            tb += b1[i]*(wt + wb);
        }
        q[64+0*16+j] = a0; q[64+1*16+j] = a1; q[64+2*16+j] = a2; q[64+3*16+j] = a3;
        q[128+0*16+j] = c0; q[128+1*16+j] = c1v; q[128+2*16+j] = c2v; q[128+3*16+j] = c3;
        q[192+j] = bm1[j] + tb;
    } else if (t < 20){
        int c = t - 16;
        float vs = 0.f, vd = 0.f, p0 = 0.f, p1 = 0.f;
        for (int i = 0; i < 16; i++){
            float w = W1[c*16 + i];
            vs += w * as1[i];
            vd += w * ad1[i];
            p0 += w * W2[i*2 + 0];
            p1 += w * W2[i*2 + 1];
        }
        q[16+c] = vs; q[20+c] = vd;
        q[28+c*2+0] = p0; q[28+c*2+1] = p1;
        sPM[c*2+0] = p0; sPM[c*2+1] = p1;
    } else if (t == 20){
        float c1 = 0.f;
        for (int k = 0; k < 3; k++){
            float g = 0.f;
            for (int j = 0; j < 16; j++) g += We1[k*16 + j] * ae1[j];
            q[4+k] = g;
            c1 += q[k] * invE * g;
        }
        q[7] = c1;
    } else if (t == 21){
        for (int k = 0; k < 4; k++)
            q[8+k] = We2[k*2] * ae2[0] + We2[k*2+1] * ae2[1];
    } else if (t == 22){
        float q0 = 0.f, q1 = 0.f;
        for (int i = 0; i < 16; i++){
            q0 += b1[i] * W2[i*2];
            q1 += b1[i] * W2[i*2+1];
        }
        q[36] = q0; q[37] = q1;
        sQ[0] = q0; sQ[1] = q1;
    }
    __syncthreads();
    if (t == 0){
        float a0 = as2[0], a1 = as2[1], d0 = ad2[0], d1 = ad2[1];
        for (int c = 0; c < 4; c++){
            q[40+c] = sPM[c*2]*a0 + sPM[c*2+1]*a1;
            q[45+c] = sPM[c*2]*d0 + sPM[c*2+1]*d1;
        }
        q[44] = sQ[0]*a0 + sQ[1]*a1;
        q[49] = sQ[0]*d0 + sQ[1]*d1;
    }
}

__global__ void __launch_bounds__(256)
k_scan1(const unsigned int* __restrict__ cnt, unsigned int* __restrict__ rowptr,
        unsigned int* __restrict__ aux, int N)
{
    __shared__ unsigned int s[256];
    int t = threadIdx.x;
    int i = blockIdx.x*256 + t;
    unsigned int v = (i < N) ? cnt[i] : 0u;
    s[t] = v;
    __syncthreads();
    for (int off = 1; off < 256; off <<= 1){
        unsigned int add = (t >= off) ? s[t-off] : 0u;
        __syncthreads();
        s[t] += add;
        __syncthreads();
    }
    if (i < N) rowptr[i] = s[t] - v;
    if (t == 255) aux[blockIdx.x] = s[t];
}

__global__ void __launch_bounds__(1024)
k_scan2(unsigned int* __restrict__ aux, int nbs)
{
    __shared__ unsigned int s[1024];
    int t = threadIdx.x;
    unsigned int v = (t < nbs) ? aux[t] : 0u;
    s[t] = v;
    __syncthreads();
    for (int off = 1; off < 1024; off <<= 1){
        unsigned int add = (t >= off) ? s[t-off] : 0u;
        __syncthreads();
        s[t] += add;
        __syncthreads();
    }
    if (t < nbs) aux[t] = s[t] - v;
}

__global__ void __launch_bounds__(256)
k_scan3(unsigned int* __restrict__ rowptr, unsigned int* __restrict__ ofs,
        const unsigned int* __restrict__ aux, int N, int E)
{
    int i = blockIdx.x*256 + threadIdx.x;
    if (i == 0) rowptr[N] = (unsigned int)E;
    if (i >= N) return;
    unsigned int r = rowptr[i] + aux[blockIdx.x];
    rowptr[i] = r;
    ofs[i] = r;   // insert pointers (used only by fallback atomic scatter)
}

__global__ void __launch_bounds__(256)
k_scatter(const int* __restrict__ ei, const float* __restrict__ ea,
          const float* __restrict__ q,
          const unsigned int* __restrict__ rowptr,
          const unsigned short* __restrict__ rank,
          unsigned int* __restrict__ ofs,
          float2* __restrict__ sg, int* __restrict__ posStash, int E)
{
    int e = blockIdx.x*256 + threadIdx.x;
    if (e >= E) return;
    int s = ei[e], d = ei[E + e];
    size_t o = 3*(size_t)e;
    float ge = ea[o]*q[4] + ea[o+1]*q[5] + ea[o+2]*q[6];
    unsigned int pos;
    if (rank){
        pos = rowptr[d] + (unsigned int)rank[e];
    } else {
        pos = atomicAdd(&ofs[d], 1u);
        posStash[4*(size_t)e] = (int)pos;
    }
    float2 r;
    r.x = __int_as_float(s);
    r.y = ge;
    sg[pos] = r;
}

// ---------- layer 1: gather, 2-way unrolled; optional h2 table ----------
__global__ void __launch_bounds__(256)
k_l1(const unsigned int* __restrict__ rowptr,
     const float2* __restrict__ sg, const float* __restrict__ x,
     const float* __restrict__ q, float* __restrict__ xagg,
     float2* __restrict__ h2t, int N)
{
    __shared__ float sq[64];
    if (threadIdx.x < 64) sq[threadIdx.x] = q[threadIdx.x];
    __syncthreads();
    int d = blockIdx.x*256 + threadIdx.x;
    if (d >= N) return;
    float4 xd = ((const float4*)x)[d];
    float hd = xd.x*sq[20] + xd.y*sq[21] + xd.z*sq[22] + xd.w*sq[23];
    float hs_self = xd.x*sq[16] + xd.y*sq[17] + xd.z*sq[18] + xd.w*sq[19];
    float p = expf(fminf(lrelu(hs_self + hd + sq[7]), 60.0f));
    float z0 = p, z1v = 0.f;
    float4 acc0, acc1;
    acc0.x = p*xd.x; acc0.y = p*xd.y; acc0.z = p*xd.z; acc0.w = p*xd.w;
    acc1.x = 0.f; acc1.y = 0.f; acc1.z = 0.f; acc1.w = 0.f;
    unsigned int beg = rowptr[d], end = rowptr[d+1];
    unsigned int j = beg;
    for (; j + 1 < end; j += 2){
        float2 r0 = sg[j];
        float2 r1 = sg[j+1];
        int s0 = __float_as_int(r0.x);
        int s1 = __float_as_int(r1.x);
        float4 xs0 = ((const float4*)x)[s0];
        float4 xs1 = ((const float4*)x)[s1];
        float av0 = xs0.x*sq[16] + xs0.y*sq[17] + xs0.z*sq[18] + xs0.w*sq[19] + hd + r0.y;
        float av1 = xs1.x*sq[16] + xs1.y*sq[17] + xs1.z*sq[18] + xs1.w*sq[19] + hd + r1.y;
        float pv0 = expf(fminf(lrelu(av0), 60.0f));
        float pv1 = expf(fminf(lrelu(av1), 60.0f));
        z0 += pv0; z1v += pv1;
        FMA4(acc0, pv0, xs0);
        FMA4(acc1, pv1, xs1);
    }
    if (j < end){
        float2 r0 = sg[j];
        int s0 = __float_as_int(r0.x);
        float4 xs0 = ((const float4*)x)[s0];
        float av0 = xs0.x*sq[16] + xs0.y*sq[17] + xs0.z*sq[18] + xs0.w*sq[19] + hd + r0.y;
        float pv0 = expf(fminf(lrelu(av0), 60.0f));
        z0 += pv0;
        FMA4(acc0, pv0, xs0);
    }
    float inv = 1.0f / (z0 + z1v);
    float4 acc;
    acc.x = (acc0.x + acc1.x) * inv;
    acc.y = (acc0.y + acc1.y) * inv;
    acc.z = (acc0.z + acc1.z) * inv;
    acc.w = (acc0.w + acc1.w) * inv;
    ((float4*)xagg)[d] = acc;
    if (h2t){
        float2 hh;
        hh.x = acc.x*sq[28] + acc.y*sq[30] + acc.z*sq[32] + acc.w*sq[34] + sq[36];
        hh.y = acc.x*sq[29] + acc.y*sq[31] + acc.z*sq[33] + acc.w*sq[35] + sq[37];
        h2t[d] = hh;
    }
}

// ---------- edge MLP: 4 edges per thread ----------
__global__ void __launch_bounds__(256)
k_mlp(const int* __restrict__ ei, const float* __restrict__ ea,
      const float* __restrict__ xagg,
      const float* __restrict__ Wm1, const float* __restrict__ Wm2,
      const float* __restrict__ bm2, const float* __restrict__ Wm3,
      const float* __restrict__ bm3, const float* __restrict__ Wm4,
      const float* __restrict__ bm4,
      const float* __restrict__ q, float* __restrict__ qw,
      float2* __restrict__ sg,
      const unsigned int* __restrict__ rowptr,
      const unsigned short* __restrict__ rank,
      const int* __restrict__ posStash,
      float* oute, int E)
{
    __shared__ __align__(16) float L[656];
    __shared__ float R[256];
    for (int t = threadIdx.x; t < 656; t += 256){
        float v;
        if      (t < 128)  v = q[64 + t];
        else if (t < 144)  v = q[192 + (t-128)];
        else if (t < 192)  v = Wm1[256 + (t-144)];
        else if (t < 448)  v = Wm2[t-192];
        else if (t < 464)  v = bm2[t-448];
        else if (t < 592)  v = Wm3[t-464];
        else if (t < 600)  v = bm3[t-592];
        else if (t < 632)  v = Wm4[t-600];
        else if (t < 636)  v = bm4[t-632];
        else if (t < 640)  v = q[8 + (t-636)];
        else               v = q[40 + (t-640)];
        L[t] = v;
    }
    __syncthreads();
    const float4* A4  = (const float4*)(L);
    const float4* B4  = (const float4*)(L + 64);
    const float4* bb4 = (const float4*)(L + 128);
    const float4* C34 = (const float4*)(L + 144);
    const float4* W24 = (const float4*)(L + 192);
    const float4* B24 = (const float4*)(L + 448);
    const float4* W34 = (const float4*)(L + 464);
    const float4* B34 = (const float4*)(L + 592);
    const float4* W44 = (const float4*)(L + 600);
    const float*  sg2v = L + 636;
    const float*  SD  = L + 640;

    int tg = blockIdx.x*256 + threadIdx.x;
    int e0 = tg*4;
    float etsum = 0.f;
    if (e0 + 3 < E){
        int4 sis = ((const int4*)ei)[tg];
        int4 dis = ((const int4*)(ei + E))[tg];
        int si[4] = { sis.x, sis.y, sis.z, sis.w };
        int di[4] = { dis.x, dis.y, dis.z, dis.w };
        float4 eA = ((const float4*)ea)[3*tg+0];
        float4 eB = ((const float4*)ea)[3*tg+1];
        float4 eC = ((const float4*)ea)[3*tg+2];
        float eaf[4][3] = {
            { eA.x, eA.y, eA.z },
            { eA.w, eB.x, eB.y },
            { eB.z, eB.w, eC.x },
            { eC.y, eC.z, eC.w }
        };
        int stash[4];
        if (rank){
            ushort4 rr = ((const ushort4*)rank)[tg];
            stash[0] = (int)(rowptr[di[0]] + rr.x);
            stash[1] = (int)(rowptr[di[1]] + rr.y);
            stash[2] = (int)(rowptr[di[2]] + rr.z);
            stash[3] = (int)(rowptr[di[3]] + rr.w);
        } else {
            #pragma unroll
            for (int k = 0; k < 4; k++)
                stash[k] = posStash[4*(size_t)(e0+k)];
        }

        float xsf[4][4], xdf[4][4], hsd[4];
        #pragma unroll
        for (int k = 0; k < 4; k++){
            float4 xs = ((const float4*)xagg)[si[k]];
            float4 xd = ((const float4*)xagg)[di[k]];
            xsf[k][0]=xs.x; xsf[k][1]=xs.y; xsf[k][2]=xs.z; xsf[k][3]=xs.w;
            xdf[k][0]=xd.x; xdf[k][1]=xd.y; xdf[k][2]=xd.z; xdf[k][3]=xd.w;
            float hs2 = xs.x*SD[0] + xs.y*SD[1] + xs.z*SD[2] + xs.w*SD[3] + SD[4];
            float hd2 = xd.x*SD[5] + xd.y*SD[6] + xd.z*SD[7] + xd.w*SD[8] + SD[9];
            hsd[k] = hs2 + hd2;
        }

        float u1[4][16];
        #pragma unroll
        for (int j4 = 0; j4 < 4; j4++){
            float4 acc0 = bb4[j4], acc1 = acc0, acc2 = acc0, acc3 = acc0;
            #pragma unroll
            for (int r = 0; r < 4; r++){
                float4 w = A4[r*4 + j4];
                FMA4(acc0, xsf[0][r], w); FMA4(acc1, xsf[1][r], w);
                FMA4(acc2, xsf[2][r], w); FMA4(acc3, xsf[3][r], w);
            }
            #pragma unroll
            for (int r = 0; r < 3; r++){
                float4 w = C34[r*4 + j4];
                FMA4(acc0, eaf[0][r], w); FMA4(acc1, eaf[1][r], w);
                FMA4(acc2, eaf[2][r], w); FMA4(acc3, eaf[3][r], w);
            }
            #pragma unroll
            for (int r = 0; r < 4; r++){
                float4 w = B4[r*4 + j4];
                FMA4(acc0, xdf[0][r], w); FMA4(acc1, xdf[1][r], w);
                FMA4(acc2, xdf[2][r], w); FMA4(acc3, xdf[3][r], w);
            }
            u1[0][j4*4+0]=fmaxf(acc0.x,0.f); u1[0][j4*4+1]=fmaxf(acc0.y,0.f);
            u1[0][j4*4+2]=fmaxf(acc0.z,0.f); u1[0][j4*4+3]=fmaxf(acc0.w,0.f);
            u1[1][j4*4+0]=fmaxf(acc1.x,0.f); u1[1][j4*4+1]=fmaxf(acc1.y,0.f);
            u1[1][j4*4+2]=fmaxf(acc1.z,0.f); u1[1][j4*4+3]=fmaxf(acc1.w,0.f);
            u1[2][j4*4+0]=fmaxf(acc2.x,0.f); u1[2][j4*4+1]=fmaxf(acc2.y,0.f);
            u1[2][j4*4+2]=fmaxf(acc2.z,0.f); u1[2][j4*4+3]=fmaxf(acc2.w,0.f);
            u1[3][j4*4+0]=fmaxf(acc3.x,0.f); u1[3][j4*4+1]=fmaxf(acc3.y,0.f);
            u1[3][j4*4+2]=fmaxf(acc3.z,0.f); u1[3][j4*4+3]=fmaxf(acc3.w,0.f);
        }

        float u2[4][16];
        #pragma unroll
        for (int j4 = 0; j4 < 4; j4++){
            float4 acc0 = B24[j4], acc1 = acc0, acc2 = acc0, acc3 = acc0;
            #pragma unroll
            for (int c = 0; c < 16; c++){
                float4 w = W24[c*4 + j4];
                FMA4(acc0, u1[0][c], w); FMA4(acc1, u1[1][c], w);
                FMA4(acc2, u1[2][c], w); FMA4(acc3, u1[3][c], w);
            }
            u2[0][j4*4+0]=fmaxf(acc0.x,0.f); u2[0][j4*4+1]=fmaxf(acc0.y,0.f);
            u2[0][j4*4+2]=fmaxf(acc0.z,0.f); u2[0][j4*4+3]=fmaxf(acc0.w,0.f);
            u2[1][j4*4+0]=fmaxf(acc1.x,0.f); u2[1][j4*4+1]=fmaxf(acc1.y,0.f);
            u2[1][j4*4+2]=fmaxf(acc1.z,0.f); u2[1][j4*4+3]=fmaxf(acc1.w,0.f);
            u2[2][j4*4+0]=fmaxf(acc2.x,0.f); u2[2][j4*4+1]=fmaxf(acc2.y,0.f);
            u2[2][j4*4+2]=fmaxf(acc2.z,0.f); u2[2][j4*4+3]=fmaxf(acc2.w,0.f);
            u2[3][j4*4+0]=fmaxf(acc3.x,0.f); u2[3][j4*4+1]=fmaxf(acc3.y,0.f);
            u2[3][j4*4+2]=fmaxf(acc3.z,0.f); u2[3][j4*4+3]=fmaxf(acc3.w,0.f);
        }

        float u3[4][8];
        #pragma unroll
        for (int j2 = 0; j2 < 2; j2++){
            float4 acc0 = B34[j2], acc1 = acc0, acc2 = acc0, acc3 = acc0;
            #pragma unroll
            for (int c = 0; c < 16; c++){
                float4 w = W34[c*2 + j2];
                FMA4(acc0, u2[0][c], w); FMA4(acc1, u2[1][c], w);
                FMA4(acc2, u2[2][c], w); FMA4(acc3, u2[3][c], w);
            }
            u3[0][j2*4+0]=fmaxf(acc0.x,0.f); u3[0][j2*4+1]=fmaxf(acc0.y,0.f);
            u3[0][j2*4+2]=fmaxf(acc0.z,0.f); u3[0][j2*4+3]=fmaxf(acc0.w,0.f);
            u3[1][j2*4+0]=fmaxf(acc1.x,0.f); u3[1][j2*4+1]=fmaxf(acc1.y,0.f);
            u3[1][j2*4+2]=fmaxf(acc1.z,0.f); u3[1][j2*4+3]=fmaxf(acc1.w,0.f);
            u3[2][j2*4+0]=fmaxf(acc2.x,0.f); u3[2][j2*4+1]=fmaxf(acc2.y,0.f);
            u3[2][j2*4+2]=fmaxf(acc2.z,0.f); u3[2][j2*4+3]=fmaxf(acc2.w,0.f);
            u3[3][j2*4+0]=fmaxf(acc3.x,0.f); u3[3][j2*4+1]=fmaxf(acc3.y,0.f);
            u3[3][j2*4+2]=fmaxf(acc3.z,0.f); u3[3][j2*4+3]=fmaxf(acc3.w,0.f);
        }

        float4 ev[4];
        {
            float4 b4v = *(const float4*)(L + 632);
            ev[0] = b4v; ev[1] = b4v; ev[2] = b4v; ev[3] = b4v;
            #pragma unroll
            for (int c = 0; c < 8; c++){
                float4 w = W44[c];
                FMA4(ev[0], u3[0][c], w); FMA4(ev[1], u3[1][c], w);
                FMA4(ev[2], u3[2][c], w); FMA4(ev[3], u3[3][c], w);
            }
        }

        #pragma unroll
        for (int k = 0; k < 4; k++){
            float4 e4 = ev[k];
            float mx = fmaxf(fmaxf(e4.x, e4.y), fmaxf(e4.z, e4.w));
            float ls = logf(expf(e4.x-mx)+expf(e4.y-mx)+expf(e4.z-mx)+expf(e4.w-mx)) + mx;
            float4 o;
            o.x = e4.x-ls; o.y = e4.y-ls; o.z = e4.z-ls; o.w = e4.w-ls;
            ((float4*)oute)[e0+k] = o;
            float et = e4.x*sg2v[0] + e4.y*sg2v[1] + e4.z*sg2v[2] + e4.w*sg2v[3];
            etsum += et;
            sg[stash[k]].y = lrelu(hsd[k] + et);
        }
    } else if (e0 < E){
        for (int e = e0; e < E; e++){
            int sp;
            if (rank) sp = (int)(rowptr[ei[E+e]] + rank[e]);
            else      sp = posStash[4*(size_t)e];
            int si = ei[e], di = ei[E+e];
            float4 xs = ((const float4*)xagg)[si];
            float4 xd = ((const float4*)xagg)[di];
            size_t eo = 3*(size_t)e;
            float e0v = ea[eo], e1v = ea[eo+1], e2v = ea[eo+2];
            float u1s[16];
            #pragma unroll
            for (int j4 = 0; j4 < 4; j4++){
                float4 acc = bb4[j4];
                FMA4(acc, xs.x, A4[0*4+j4]); FMA4(acc, xs.y, A4[1*4+j4]);
                FMA4(acc, xs.z, A4[2*4+j4]); FMA4(acc, xs.w, A4[3*4+j4]);
                FMA4(acc, e0v, C34[0*4+j4]); FMA4(acc, e1v, C34[1*4+j4]);
                FMA4(acc, e2v, C34[2*4+j4]);
                FMA4(acc, xd.x, B4[0*4+j4]); FMA4(acc, xd.y, B4[1*4+j4]);
                FMA4(acc, xd.z, B4[2*4+j4]); FMA4(acc, xd.w, B4[3*4+j4]);
                u1s[j4*4+0]=fmaxf(acc.x,0.f); u1s[j4*4+1]=fmaxf(acc.y,0.f);
                u1s[j4*4+2]=fmaxf(acc.z,0.f); u1s[j4*4+3]=fmaxf(acc.w,0.f);
            }
            float u2s[16];
            #pragma unroll
            for (int j4 = 0; j4 < 4; j4++){
                float4 acc = B24[j4];
                #pragma unroll
                for (int c = 0; c < 16; c++) FMA4(acc, u1s[c], W24[c*4+j4]);
                u2s[j4*4+0]=fmaxf(acc.x,0.f); u2s[j4*4+1]=fmaxf(acc.y,0.f);
                u2s[j4*4+2]=fmaxf(acc.z,0.f); u2s[j4*4+3]=fmaxf(acc.w,0.f);
            }
            float u3s[8];
            #pragma unroll
            for (int j2 = 0; j2 < 2; j2++){
                float4 acc = B34[j2];
                #pragma unroll
                for (int c = 0; c < 16; c++) FMA4(acc, u2s[c], W34[c*2+j2]);
                u3s[j2*4+0]=fmaxf(acc.x,0.f); u3s[j2*4+1]=fmaxf(acc.y,0.f);
                u3s[j2*4+2]=fmaxf(acc.z,0.f); u3s[j2*4+3]=fmaxf(acc.w,0.f);
            }
            float4 e4 = *(const float4*)(L + 632);
            #pragma unroll
            for (int c = 0; c < 8; c++) FMA4(e4, u3s[c], W44[c]);
            float mx = fmaxf(fmaxf(e4.x, e4.y), fmaxf(e4.z, e4.w));
            float ls = logf(expf(e4.x-mx)+expf(e4.y-mx)+expf(e4.z-mx)+expf(e4.w-mx)) + mx;
            float4 o;
            o.x = e4.x-ls; o.y = e4.y-ls; o.z = e4.z-ls; o.w = e4.w-ls;
            ((float4*)oute)[e] = o;
            float et = e4.x*sg2v[0] + e4.y*sg2v[1] + e4.z*sg2v[2] + e4.w*sg2v[3];
            etsum += et;
            float hs2 = xs.x*SD[0] + xs.y*SD[1] + xs.z*SD[2] + xs.w*SD[3] + SD[4];
            float hd2 = xd.x*SD[5] + xd.y*SD[6] + xd.z*SD[7] + xd.w*SD[8] + SD[9];
            sg[sp].y = lrelu(hs2 + hd2 + et);
        }
    }
    R[threadIdx.x] = etsum;
    __syncthreads();
    for (int off = 128; off > 0; off >>= 1){
        if (threadIdx.x < off) R[threadIdx.x] += R[threadIdx.x + off];
        __syncthreads();
    }
    if (threadIdx.x == 0) atomicAdd(&qw[3], R[0]);
}

// ---------- layer 2: single-pass online softmax, fused output ----------
__global__ void __launch_bounds__(256)
k_l2(const unsigned int* __restrict__ rowptr,
     const float2* __restrict__ sg, const float* __restrict__ xagg,
     const float2* __restrict__ h2t,
     const float* __restrict__ q, const float* __restrict__ b2,
     float* __restrict__ outn, float invE, int N)
{
    __shared__ float sq[64];
    if (threadIdx.x < 64) sq[threadIdx.x] = q[threadIdx.x];
    __syncthreads();
    int d = blockIdx.x*256 + threadIdx.x;
    if (d >= N) return;
    float c2 = sq[3] * invE;
    float4 xa = ((const float4*)xagg)[d];
    float h2d0 = xa.x*sq[28] + xa.y*sq[30] + xa.z*sq[32] + xa.w*sq[34] + sq[36];
    float h2d1 = xa.x*sq[29] + xa.y*sq[31] + xa.z*sq[33] + xa.w*sq[35] + sq[37];
    float hs2 = xa.x*sq[40] + xa.y*sq[41] + xa.z*sq[42] + xa.w*sq[43] + sq[44];
    float hd2 = xa.x*sq[45] + xa.y*sq[46] + xa.z*sq[47] + xa.w*sq[48] + sq[49];
    float aself = lrelu(hs2 + hd2 + c2);

    float mA = aself, zA = 1.f, a0A = h2d0, a1A = h2d1;
    float mB = -1e30f, zB = 0.f, a0B = 0.f, a1B = 0.f;

    unsigned int beg = rowptr[d], end = rowptr[d+1];
    unsigned int j = beg;
    for (; j + 1 < end; j += 2){
        float2 r0 = sg[j];
        float2 r1 = sg[j+1];
        int s0 = __float_as_int(r0.x);
        int s1 = __float_as_int(r1.x);
        float h00, h01, h10, h11;
        if (h2t){
            float2 hh0 = h2t[s0];
            float2 hh1 = h2t[s1];
            h00 = hh0.x; h01 = hh0.y; h10 = hh1.x; h11 = hh1.y;
        } else {
            float4 xs0 = ((const float4*)xagg)[s0];
            float4 xs1 = ((const float4*)xagg)[s1];
            h00 = xs0.x*sq[28] + xs0.y*sq[30] + xs0.z*sq[32] + xs0.w*sq[34] + sq[36];
            h01 = xs0.x*sq[29] + xs0.y*sq[31] + xs0.z*sq[33] + xs0.w*sq[35] + sq[37];
            h10 = xs1.x*sq[28] + xs1.y*sq[30] + xs1.z*sq[32] + xs1.w*sq[34] + sq[36];
            h11 = xs1.x*sq[29] + xs1.y*sq[31] + xs1.z*sq[33] + xs1.w*sq[35] + sq[37];
        }
        float mn0 = fmaxf(mA, r0.y);
        float sc0 = expf(mA - mn0);
        float p0  = expf(r0.y - mn0);
        zA  = zA*sc0 + p0;
        a0A = a0A*sc0 + p0*h00;
        a1A = a1A*sc0 + p0*h01;
        mA = mn0;
        float mn1 = fmaxf(mB, r1.y);
        float sc1 = expf(mB - mn1);
        float p1  = expf(r1.y - mn1);
        zB  = zB*sc1 + p1;
        a0B = a0B*sc1 + p1*h10;
        a1B = a1B*sc1 + p1*h11;
        mB = mn1;
    }
    if (j < end){
        float2 r0 = sg[j];
        int s0 = __float_as_int(r0.x);
        float h00, h01;
        if (h2t){
            float2 hh0 = h2t[s0];
            h00 = hh0.x; h01 = hh0.y;
        } else {
            float4 xs0 = ((const float4*)xagg)[s0];
            h00 = xs0.x*sq[28] + xs0.y*sq[30] + xs0.z*sq[32] + xs0.w*sq[34] + sq[36];
            h01 = xs0.x*sq[29] + xs0.y*sq[31] + xs0.z*sq[33] + xs0.w*sq[35] + sq[37];
        }
        float mn0 = fmaxf(mA, r0.y);
        float sc0 = expf(mA - mn0);
        float p0  = expf(r0.y - mn0);
        zA  = zA*sc0 + p0;
        a0A = a0A*sc0 + p0*h00;
        a1A = a1A*sc0 + p0*h01;
        mA = mn0;
    }
    float m = fmaxf(mA, mB);
    float sA = expf(mA - m), sB = expf(mB - m);
    float z = zA*sA + zB*sB;
    float inv = 1.0f / z;
    float v0 = (a0A*sA + a0B*sB)*inv + b2[0];
    float v1 = (a1A*sA + a1B*sB)*inv + b2[1];
    float mm = fmaxf(v0, v1);
    float ls = logf(expf(v0-mm) + expf(v1-mm)) + mm;
    float2 o;
    o.x = v0 - ls;
    o.y = v1 - ls;
    ((float2*)outn)[d] = o;
}

extern "C" void kernel_launch(void* const* d_in, const int* in_sizes, int n_in,
                              void* d_out, int out_size, void* d_ws, size_t ws_size,
                              hipStream_t stream)
{
    const float* x   = (const float*)d_in[0];
    const int*   ei  = (const int*)  d_in[1];
    const float* ea  = (const float*)d_in[2];
    const float* W1  = (const float*)d_in[3];
    const float* as1 = (const float*)d_in[4];
    const float* ad1 = (const float*)d_in[5];
    const float* We1 = (const float*)d_in[6];
    const float* ae1 = (const float*)d_in[7];
    const float* b1  = (const float*)d_in[8];
    const float* Wm1 = (const float*)d_in[9];
    const float* bm1 = (const float*)d_in[10];
    const float* Wm2 = (const float*)d_in[11];
    const float* bm2 = (const float*)d_in[12];
    const float* Wm3 = (const float*)d_in[13];
    const float* bm3 = (const float*)d_in[14];
    const float* Wm4 = (const float*)d_in[15];
    const float* bm4 = (const float*)d_in[16];
    const float* W2  = (const float*)d_in[17];
    const float* as2 = (const float*)d_in[18];
    const float* ad2 = (const float*)d_in[19];
    const float* We2 = (const float*)d_in[20];
    const float* ae2 = (const float*)d_in[21];
    const float* b2  = (const float*)d_in[22];

    const int N = in_sizes[0] / 4;
    const int E = in_sizes[1] / 2;

    int nb_n = (N + 255) / 256;
    int nb_e = (E + 255) / 256;
    int nb_e4 = (E + 1023) / 1024;
    if (nb_n > 1024) return;

    // common: q(256) | cnt(N u32) | rowptr(N+64 u32) | aux(1024 u32) | xagg(4N) | sg(2E)
    size_t commonFloats = 256 + (size_t)N + ((size_t)N + 64) + 1024 + 4*(size_t)N + 2*(size_t)E;
    // upgraded: + h2t(2N) + rank(E u16 -> E/2+16 floats)
    size_t upFloats = commonFloats + 2*(size_t)N + ((size_t)E/2 + 16);
    if (ws_size < commonFloats*sizeof(float)) return;
    bool up = (ws_size >= upFloats*sizeof(float));

    float* ws = (float*)d_ws;
    float* q  = ws;
    unsigned int* cnt    = (unsigned int*)(ws + 256);
    unsigned int* rowptr = cnt + N;
    unsigned int* aux    = rowptr + N + 64;
    float* xagg = (float*)(aux + 1024);
    float2* sg  = (float2*)(xagg + 4*(size_t)N);
    float2* h2t = nullptr;
    unsigned short* rank = nullptr;
    if (up){
        h2t  = (float2*)(sg + (size_t)E);
        rank = (unsigned short*)(h2t + (size_t)N);
    }

    float* outn = (float*)d_out;
    float* oute = outn + 2*(size_t)N;
    int* posStash = (int*)oute;   // fallback stash (each edge's own oute slot)

    // zero q + cnt
    hipMemsetAsync(d_ws, 0, (256 + (size_t)N)*sizeof(float), stream);

    float invE = 1.0f / (float)E;

    k_hist<<<512,256,0,stream>>>(ei, ea, q, cnt, rank, E);
    k_prep<<<1,64,0,stream>>>(W1, as1, ad1, We1, ae1, b1, Wm1, bm1,
                              W2, as2, ad2, We2, ae2, q, invE);
    k_scan1<<<nb_n,256,0,stream>>>(cnt, rowptr, aux, N);
    k_scan2<<<1,1024,0,stream>>>(aux, nb_n);
    k_scan3<<<nb_n,256,0,stream>>>(rowptr, cnt, aux, N, E);   // cnt becomes insert ptrs (fallback)
    k_scatter<<<nb_e,256,0,stream>>>(ei, ea, q, rowptr, rank, cnt, sg, posStash, E);
    k_l1<<<nb_n,256,0,stream>>>(rowptr, sg, x, q, xagg, h2t, N);
    k_mlp<<<nb_e4,256,0,stream>>>(ei, ea, xagg, Wm1, Wm2, bm2, Wm3, bm3,
                                  Wm4, bm4, q, q, sg, rowptr, rank, posStash, oute, E);
    k_l2<<<nb_n,256,0,stream>>>(rowptr, sg, xagg, h2t, q, b2, outn, invE, N);
}

// Round 22
// 565.237 us; speedup vs baseline: 1.9165x; 1.0466x over previous
//
#include <hip/hip_runtime.h>
#include <hip/hip_bf16.h>

static __device__ __forceinline__ float lrelu(float v){ return v >= 0.f ? v : 0.2f*v; }

#define FMA4(D_, S_, V_) { D_.x += (S_)*(V_).x; D_.y += (S_)*(V_).y; \
                           D_.z += (S_)*(V_).z; D_.w += (S_)*(V_).w; }

// q slots (256 floats):
// 0..2 sum(ea cols) | 3 sum(et2) | 4..6 g1 | 7 c1 | 8..11 g2
// 16..19 vs1 | 20..23 vd1 | 28..35 PM | 36..37 Q
// 40..43 S | 44 s0 | 45..48 D | 49 d0
// 64..127 A=W1@Wm1_top | 128..191 B=W1@Wm1_bot | 192..207 bb

// merged: ea column sums + dst histogram (+ optional rank record)
__global__ void __launch_bounds__(256)
k_hist(const int* __restrict__ ei, const float* __restrict__ ea,
       float* __restrict__ q, unsigned int* __restrict__ cnt,
       unsigned short* __restrict__ rank, int E)
{
    float s0 = 0.f, s1 = 0.f, s2 = 0.f;
    int stride = gridDim.x * blockDim.x;
    for (int e = blockIdx.x*blockDim.x + threadIdx.x; e < E; e += stride){
        size_t o = 3*(size_t)e;
        s0 += ea[o]; s1 += ea[o+1]; s2 += ea[o+2];
        unsigned int r = atomicAdd(&cnt[ei[E + e]], 1u);
        if (rank) rank[e] = (unsigned short)r;
    }
    for (int o = 32; o > 0; o >>= 1){
        s0 += __shfl_down(s0, o);
        s1 += __shfl_down(s1, o);
        s2 += __shfl_down(s2, o);
    }
    if ((threadIdx.x & 63) == 0){
        atomicAdd(&q[0], s0); atomicAdd(&q[1], s1); atomicAdd(&q[2], s2);
    }
}

__global__ void
k_prep(const float* __restrict__ W1, const float* __restrict__ as1,
       const float* __restrict__ ad1,
       const float* __restrict__ We1, const float* __restrict__ ae1,
       const float* __restrict__ b1,
       const float* __restrict__ Wm1, const float* __restrict__ bm1,
       const float* __restrict__ W2, const float* __restrict__ as2,
       const float* __restrict__ ad2,
       const float* __restrict__ We2, const float* __restrict__ ae2,
       float* __restrict__ q, float invE)
{
    __shared__ float sPM[8], sQ[2];
    int t = threadIdx.x;
    if (t < 16){
        int j = t;
        float a0=0,a1=0,a2=0,a3=0, c0=0,c1v=0,c2v=0,c3=0, tb=0;
        for (int i = 0; i < 16; i++){
            float wt = Wm1[i*16 + j];
            float wb = Wm1[(19+i)*16 + j];
            a0 += W1[0*16+i]*wt; a1 += W1[1*16+i]*wt;
            a2 += W1[2*16+i]*wt; a3 += W1[3*16+i]*wt;
            c0 += W1[0*16+i]*wb; c1v += W1[1*16+i]*wb;
            c2v += W1[2*16+i]*wb; c3 += W1[3*16+i]*wb;
            tb += b1[i]*(wt + wb);
        }
        q[64+0*16+j] = a0; q[64+1*16+j] = a1; q[64+2*16+j] = a2; q[64+3*16+j] = a3;
        q[128+0*16+j] = c0; q[128+1*16+j] = c1v; q[128+2*16+j] = c2v; q[128+3*16+j] = c3;
        q[192+j] = bm1[j] + tb;
    } else if (t < 20){
        int c = t - 16;
        float vs = 0.f, vd = 0.f, p0 = 0.f, p1 = 0.f;
        for (int i = 0; i < 16; i++){
            float w = W1[c*16 + i];
            vs += w * as1[i];
            vd += w * ad1[i];
            p0 += w * W2[i*2 + 0];
            p1 += w * W2[i*2 + 1];
        }
        q[16+c] = vs; q[20+c] = vd;
        q[28+c*2+0] = p0; q[28+c*2+1] = p1;
        sPM[c*2+0] = p0; sPM[c*2+1] = p1;
    } else if (t == 20){
        float c1 = 0.f;
        for (int k = 0; k < 3; k++){
            float g = 0.f;
            for (int j = 0; j < 16; j++) g += We1[k*16 + j] * ae1[j];
            q[4+k] = g;
            c1 += q[k] * invE * g;
        }
        q[7] = c1;
    } else if (t == 21){
        for (int k = 0; k < 4; k++)
            q[8+k] = We2[k*2] * ae2[0] + We2[k*2+1] * ae2[1];
    } else if (t == 22){
        float q0 = 0.f, q1 = 0.f;
        for (int i = 0; i < 16; i++){
            q0 += b1[i] * W2[i*2];
            q1 += b1[i] * W2[i*2+1];
        }
        q[36] = q0; q[37] = q1;
        sQ[0] = q0; sQ[1] = q1;
    }
    __syncthreads();
    if (t == 0){
        float a0 = as2[0], a1 = as2[1], d0 = ad2[0], d1 = ad2[1];
        for (int c = 0; c < 4; c++){
            q[40+c] = sPM[c*2]*a0 + sPM[c*2+1]*a1;
            q[45+c] = sPM[c*2]*d0 + sPM[c*2+1]*d1;
        }
        q[44] = sQ[0]*a0 + sQ[1]*a1;
        q[49] = sQ[0]*d0 + sQ[1]*d1;
    }
}

__global__ void __launch_bounds__(256)
k_scan1(const unsigned int* __restrict__ cnt, unsigned int* __restrict__ rowptr,
        unsigned int* __restrict__ aux, int N)
{
    __shared__ unsigned int s[256];
    int t = threadIdx.x;
    int i = blockIdx.x*256 + t;
    unsigned int v = (i < N) ? cnt[i] : 0u;
    s[t] = v;
    __syncthreads();
    for (int off = 1; off < 256; off <<= 1){
        unsigned int add = (t >= off) ? s[t-off] : 0u;
        __syncthreads();
        s[t] += add;
        __syncthreads();
    }
    if (i < N) rowptr[i] = s[t] - v;
    if (t == 255) aux[blockIdx.x] = s[t];
}

__global__ void __launch_bounds__(1024)
k_scan2(unsigned int* __restrict__ aux, int nbs)
{
    __shared__ unsigned int s[1024];
    int t = threadIdx.x;
    unsigned int v = (t < nbs) ? aux[t] : 0u;
    s[t] = v;
    __syncthreads();
    for (int off = 1; off < 1024; off <<= 1){
        unsigned int add = (t >= off) ? s[t-off] : 0u;
        __syncthreads();
        s[t] += add;
        __syncthreads();
    }
    if (t < nbs) aux[t] = s[t] - v;
}

__global__ void __launch_bounds__(256)
k_scan3(unsigned int* __restrict__ rowptr, unsigned int* __restrict__ ofs,
        const unsigned int* __restrict__ aux, int N, int E)
{
    int i = blockIdx.x*256 + threadIdx.x;
    if (i == 0) rowptr[N] = (unsigned int)E;
    if (i >= N) return;
    unsigned int r = rowptr[i] + aux[blockIdx.x];
    rowptr[i] = r;
    ofs[i] = r;   // insert pointers (used only by fallback atomic scatter)
}

__global__ void __launch_bounds__(256)
k_scatter(const int* __restrict__ ei, const float* __restrict__ ea,
          const float* __restrict__ q,
          const unsigned int* __restrict__ rowptr,
          const unsigned short* __restrict__ rank,
          unsigned int* __restrict__ ofs,
          float2* __restrict__ sg, int* __restrict__ posStash, int E)
{
    int e = blockIdx.x*256 + threadIdx.x;
    if (e >= E) return;
    int s = ei[e], d = ei[E + e];
    size_t o = 3*(size_t)e;
    float ge = ea[o]*q[4] + ea[o+1]*q[5] + ea[o+2]*q[6];
    unsigned int pos;
    if (rank){
        pos = rowptr[d] + (unsigned int)rank[e];
    } else {
        pos = atomicAdd(&ofs[d], 1u);
        posStash[4*(size_t)e] = (int)pos;
    }
    float2 r;
    r.x = __int_as_float(s);
    r.y = ge;
    sg[pos] = r;
}

// ---------- layer 1: gather, 2-way unrolled; optional h2 table ----------
__global__ void __launch_bounds__(256)
k_l1(const unsigned int* __restrict__ rowptr,
     const float2* __restrict__ sg, const float* __restrict__ x,
     const float* __restrict__ q, float* __restrict__ xagg,
     float2* __restrict__ h2t, int N)
{
    __shared__ float sq[64];
    if (threadIdx.x < 64) sq[threadIdx.x] = q[threadIdx.x];
    __syncthreads();
    int d = blockIdx.x*256 + threadIdx.x;
    if (d >= N) return;
    float4 xd = ((const float4*)x)[d];
    float hd = xd.x*sq[20] + xd.y*sq[21] + xd.z*sq[22] + xd.w*sq[23];
    float hs_self = xd.x*sq[16] + xd.y*sq[17] + xd.z*sq[18] + xd.w*sq[19];
    float p = expf(fminf(lrelu(hs_self + hd + sq[7]), 60.0f));
    float z0 = p, z1v = 0.f;
    float4 acc0, acc1;
    acc0.x = p*xd.x; acc0.y = p*xd.y; acc0.z = p*xd.z; acc0.w = p*xd.w;
    acc1.x = 0.f; acc1.y = 0.f; acc1.z = 0.f; acc1.w = 0.f;
    unsigned int beg = rowptr[d], end = rowptr[d+1];
    unsigned int j = beg;
    for (; j + 1 < end; j += 2){
        float2 r0 = sg[j];
        float2 r1 = sg[j+1];
        int s0 = __float_as_int(r0.x);
        int s1 = __float_as_int(r1.x);
        float4 xs0 = ((const float4*)x)[s0];
        float4 xs1 = ((const float4*)x)[s1];
        float av0 = xs0.x*sq[16] + xs0.y*sq[17] + xs0.z*sq[18] + xs0.w*sq[19] + hd + r0.y;
        float av1 = xs1.x*sq[16] + xs1.y*sq[17] + xs1.z*sq[18] + xs1.w*sq[19] + hd + r1.y;
        float pv0 = expf(fminf(lrelu(av0), 60.0f));
        float pv1 = expf(fminf(lrelu(av1), 60.0f));
        z0 += pv0; z1v += pv1;
        FMA4(acc0, pv0, xs0);
        FMA4(acc1, pv1, xs1);
    }
    if (j < end){
        float2 r0 = sg[j];
        int s0 = __float_as_int(r0.x);
        float4 xs0 = ((const float4*)x)[s0];
        float av0 = xs0.x*sq[16] + xs0.y*sq[17] + xs0.z*sq[18] + xs0.w*sq[19] + hd + r0.y;
        float pv0 = expf(fminf(lrelu(av0), 60.0f));
        z0 += pv0;
        FMA4(acc0, pv0, xs0);
    }
    float inv = 1.0f / (z0 + z1v);
    float4 acc;
    acc.x = (acc0.x + acc1.x) * inv;
    acc.y = (acc0.y + acc1.y) * inv;
    acc.z = (acc0.z + acc1.z) * inv;
    acc.w = (acc0.w + acc1.w) * inv;
    ((float4*)xagg)[d] = acc;
    if (h2t){
        float2 hh;
        hh.x = acc.x*sq[28] + acc.y*sq[30] + acc.z*sq[32] + acc.w*sq[34] + sq[36];
        hh.y = acc.x*sq[29] + acc.y*sq[31] + acc.z*sq[33] + acc.w*sq[35] + sq[37];
        h2t[d] = hh;
    }
}

// ---------- edge MLP: 4 edges per thread ----------
__global__ void __launch_bounds__(256)
k_mlp(const int* __restrict__ ei, const float* __restrict__ ea,
      const float* __restrict__ xagg,
      const float* __restrict__ Wm1, const float* __restrict__ Wm2,
      const float* __restrict__ bm2, const float* __restrict__ Wm3,
      const float* __restrict__ bm3, const float* __restrict__ Wm4,
      const float* __restrict__ bm4,
      const float* __restrict__ q, float* __restrict__ qw,
      float2* __restrict__ sg,
      const unsigned int* __restrict__ rowptr,
      const unsigned short* __restrict__ rank,
      const int* __restrict__ posStash,
      float* oute, int E)
{
    __shared__ __align__(16) float L[656];
    __shared__ float R[256];
    for (int t = threadIdx.x; t < 656; t += 256){
        float v;
        if      (t < 128)  v = q[64 + t];
        else if (t < 144)  v = q[192 + (t-128)];
        else if (t < 192)  v = Wm1[256 + (t-144)];
        else if (t < 448)  v = Wm2[t-192];
        else if (t < 464)  v = bm2[t-448];
        else if (t < 592)  v = Wm3[t-464];
        else if (t < 600)  v = bm3[t-592];
        else if (t < 632)  v = Wm4[t-600];
        else if (t < 636)  v = bm4[t-632];
        else if (t < 640)  v = q[8 + (t-636)];
        else               v = q[40 + (t-640)];
        L[t] = v;
    }
    __syncthreads();
    const float4* A4  = (const float4*)(L);
    const float4* B4  = (const float4*)(L + 64);
    const float4* bb4 = (const float4*)(L + 128);
    const float4* C34 = (const float4*)(L + 144);
    const float4* W24 = (const float4*)(L + 192);
    const float4* B24 = (const float4*)(L + 448);
    const float4* W34 = (const float4*)(L + 464);
    const float4* B34 = (const float4*)(L + 592);
    const float4* W44 = (const float4*)(L + 600);
    const float*  sg2v = L + 636;
    const float*  SD  = L + 640;

    int tg = blockIdx.x*256 + threadIdx.x;
    int e0 = tg*4;
    float etsum = 0.f;
    if (e0 + 3 < E){
        int4 sis = ((const int4*)ei)[tg];
        int4 dis = ((const int4*)(ei + E))[tg];
        int si[4] = { sis.x, sis.y, sis.z, sis.w };
        int di[4] = { dis.x, dis.y, dis.z, dis.w };
        float4 eA = ((const float4*)ea)[3*tg+0];
        float4 eB = ((const float4*)ea)[3*tg+1];
        float4 eC = ((const float4*)ea)[3*tg+2];
        float eaf[4][3] = {
            { eA.x, eA.y, eA.z },
            { eA.w, eB.x, eB.y },
            { eB.z, eB.w, eC.x },
            { eC.y, eC.z, eC.w }
        };
        int stash[4];
        if (rank){
            ushort4 rr = ((const ushort4*)rank)[tg];
            stash[0] = (int)(rowptr[di[0]] + rr.x);
            stash[1] = (int)(rowptr[di[1]] + rr.y);
            stash[2] = (int)(rowptr[di[2]] + rr.z);
            stash[3] = (int)(rowptr[di[3]] + rr.w);
        } else {
            #pragma unroll
            for (int k = 0; k < 4; k++)
                stash[k] = posStash[4*(size_t)(e0+k)];
        }

        float xsf[4][4], xdf[4][4], hsd[4];
        #pragma unroll
        for (int k = 0; k < 4; k++){
            float4 xs = ((const float4*)xagg)[si[k]];
            float4 xd = ((const float4*)xagg)[di[k]];
            xsf[k][0]=xs.x; xsf[k][1]=xs.y; xsf[k][2]=xs.z; xsf[k][3]=xs.w;
            xdf[k][0]=xd.x; xdf[k][1]=xd.y; xdf[k][2]=xd.z; xdf[k][3]=xd.w;
            float hs2 = xs.x*SD[0] + xs.y*SD[1] + xs.z*SD[2] + xs.w*SD[3] + SD[4];
            float hd2 = xd.x*SD[5] + xd.y*SD[6] + xd.z*SD[7] + xd.w*SD[8] + SD[9];
            hsd[k] = hs2 + hd2;
        }

        float u1[4][16];
        #pragma unroll
        for (int j4 = 0; j4 < 4; j4++){
            float4 acc0 = bb4[j4], acc1 = acc0, acc2 = acc0, acc3 = acc0;
            #pragma unroll
            for (int r = 0; r < 4; r++){
                float4 w = A4[r*4 + j4];
                FMA4(acc0, xsf[0][r], w); FMA4(acc1, xsf[1][r], w);
                FMA4(acc2, xsf[2][r], w); FMA4(acc3, xsf[3][r], w);
            }
            #pragma unroll
            for (int r = 0; r < 3; r++){
                float4 w = C34[r*4 + j4];
                FMA4(acc0, eaf[0][r], w); FMA4(acc1, eaf[1][r], w);
                FMA4(acc2, eaf[2][r], w); FMA4(acc3, eaf[3][r], w);
            }
            #pragma unroll
            for (int r = 0; r < 4; r++){
                float4 w = B4[r*4 + j4];
                FMA4(acc0, xdf[0][r], w); FMA4(acc1, xdf[1][r], w);
                FMA4(acc2, xdf[2][r], w); FMA4(acc3, xdf[3][r], w);
            }
            u1[0][j4*4+0]=fmaxf(acc0.x,0.f); u1[0][j4*4+1]=fmaxf(acc0.y,0.f);
            u1[0][j4*4+2]=fmaxf(acc0.z,0.f); u1[0][j4*4+3]=fmaxf(acc0.w,0.f);
            u1[1][j4*4+0]=fmaxf(acc1.x,0.f); u1[1][j4*4+1]=fmaxf(acc1.y,0.f);
            u1[1][j4*4+2]=fmaxf(acc1.z,0.f); u1[1][j4*4+3]=fmaxf(acc1.w,0.f);
            u1[2][j4*4+0]=fmaxf(acc2.x,0.f); u1[2][j4*4+1]=fmaxf(acc2.y,0.f);
            u1[2][j4*4+2]=fmaxf(acc2.z,0.f); u1[2][j4*4+3]=fmaxf(acc2.w,0.f);
            u1[3][j4*4+0]=fmaxf(acc3.x,0.f); u1[3][j4*4+1]=fmaxf(acc3.y,0.f);
            u1[3][j4*4+2]=fmaxf(acc3.z,0.f); u1[3][j4*4+3]=fmaxf(acc3.w,0.f);
        }

        float u2[4][16];
        #pragma unroll
        for (int j4 = 0; j4 < 4; j4++){
            float4 acc0 = B24[j4], acc1 = acc0, acc2 = acc0, acc3 = acc0;
            #pragma unroll
            for (int c = 0; c < 16; c++){
                float4 w = W24[c*4 + j4];
                FMA4(acc0, u1[0][c], w); FMA4(acc1, u1[1][c], w);
                FMA4(acc2, u1[2][c], w); FMA4(acc3, u1[3][c], w);
            }
            u2[0][j4*4+0]=fmaxf(acc0.x,0.f); u2[0][j4*4+1]=fmaxf(acc0.y,0.f);
            u2[0][j4*4+2]=fmaxf(acc0.z,0.f); u2[0][j4*4+3]=fmaxf(acc0.w,0.f);
            u2[1][j4*4+0]=fmaxf(acc1.x,0.f); u2[1][j4*4+1]=fmaxf(acc1.y,0.f);
            u2[1][j4*4+2]=fmaxf(acc1.z,0.f); u2[1][j4*4+3]=fmaxf(acc1.w,0.f);
            u2[2][j4*4+0]=fmaxf(acc2.x,0.f); u2[2][j4*4+1]=fmaxf(acc2.y,0.f);
            u2[2][j4*4+2]=fmaxf(acc2.z,0.f); u2[2][j4*4+3]=fmaxf(acc2.w,0.f);
            u2[3][j4*4+0]=fmaxf(acc3.x,0.f); u2[3][j4*4+1]=fmaxf(acc3.y,0.f);
            u2[3][j4*4+2]=fmaxf(acc3.z,0.f); u2[3][j4*4+3]=fmaxf(acc3.w,0.f);
        }

        float u3[4][8];
        #pragma unroll
        for (int j2 = 0; j2 < 2; j2++){
            float4 acc0 = B34[j2], acc1 = acc0, acc2 = acc0, acc3 = acc0;
            #pragma unroll
            for (int c = 0; c < 16; c++){
                float4 w = W34[c*2 + j2];
                FMA4(acc0, u2[0][c], w); FMA4(acc1, u2[1][c], w);
                FMA4(acc2, u2[2][c], w); FMA4(acc3, u2[3][c], w);
            }
            u3[0][j2*4+0]=fmaxf(acc0.x,0.f); u3[0][j2*4+1]=fmaxf(acc0.y,0.f);
            u3[0][j2*4+2]=fmaxf(acc0.z,0.f); u3[0][j2*4+3]=fmaxf(acc0.w,0.f);
            u3[1][j2*4+0]=fmaxf(acc1.x,0.f); u3[1][j2*4+1]=fmaxf(acc1.y,0.f);
            u3[1][j2*4+2]=fmaxf(acc1.z,0.f); u3[1][j2*4+3]=fmaxf(acc1.w,0.f);
            u3[2][j2*4+0]=fmaxf(acc2.x,0.f); u3[2][j2*4+1]=fmaxf(acc2.y,0.f);
            u3[2][j2*4+2]=fmaxf(acc2.z,0.f); u3[2][j2*4+3]=fmaxf(acc2.w,0.f);
            u3[3][j2*4+0]=fmaxf(acc3.x,0.f); u3[3][j2*4+1]=fmaxf(acc3.y,0.f);
            u3[3][j2*4+2]=fmaxf(acc3.z,0.f); u3[3][j2*4+3]=fmaxf(acc3.w,0.f);
        }

        float4 ev[4];
        {
            float4 b4v = *(const float4*)(L + 632);
            ev[0] = b4v; ev[1] = b4v; ev[2] = b4v; ev[3] = b4v;
            #pragma unroll
            for (int c = 0; c < 8; c++){
                float4 w = W44[c];
                FMA4(ev[0], u3[0][c], w); FMA4(ev[1], u3[1][c], w);
                FMA4(ev[2], u3[2][c], w); FMA4(ev[3], u3[3][c], w);
            }
        }

        #pragma unroll
        for (int k = 0; k < 4; k++){
            float4 e4 = ev[k];
            float mx = fmaxf(fmaxf(e4.x, e4.y), fmaxf(e4.z, e4.w));
            float ls = logf(expf(e4.x-mx)+expf(e4.y-mx)+expf(e4.z-mx)+expf(e4.w-mx)) + mx;
            float4 o;
            o.x = e4.x-ls; o.y = e4.y-ls; o.z = e4.z-ls; o.w = e4.w-ls;
            ((float4*)oute)[e0+k] = o;
            float et = e4.x*sg2v[0] + e4.y*sg2v[1] + e4.z*sg2v[2] + e4.w*sg2v[3];
            etsum += et;
            sg[stash[k]].y = lrelu(hsd[k] + et);
        }
    } else if (e0 < E){
        for (int e = e0; e < E; e++){
            int sp;
            if (rank) sp = (int)(rowptr[ei[E+e]] + rank[e]);
            else      sp = posStash[4*(size_t)e];
            int si = ei[e], di = ei[E+e];
            float4 xs = ((const float4*)xagg)[si];
            float4 xd = ((const float4*)xagg)[di];
            size_t eo = 3*(size_t)e;
            float e0v = ea[eo], e1v = ea[eo+1], e2v = ea[eo+2];
            float u1s[16];
            #pragma unroll
            for (int j4 = 0; j4 < 4; j4++){
                float4 acc = bb4[j4];
                FMA4(acc, xs.x, A4[0*4+j4]); FMA4(acc, xs.y, A4[1*4+j4]);
                FMA4(acc, xs.z, A4[2*4+j4]); FMA4(acc, xs.w, A4[3*4+j4]);
                FMA4(acc, e0v, C34[0*4+j4]); FMA4(acc, e1v, C34[1*4+j4]);
                FMA4(acc, e2v, C34[2*4+j4]);
                FMA4(acc, xd.x, B4[0*4+j4]); FMA4(acc, xd.y, B4[1*4+j4]);
                FMA4(acc, xd.z, B4[2*4+j4]); FMA4(acc, xd.w, B4[3*4+j4]);
                u1s[j4*4+0]=fmaxf(acc.x,0.f); u1s[j4*4+1]=fmaxf(acc.y,0.f);
                u1s[j4*4+2]=fmaxf(acc.z,0.f); u1s[j4*4+3]=fmaxf(acc.w,0.f);
            }
            float u2s[16];
            #pragma unroll
            for (int j4 = 0; j4 < 4; j4++){
                float4 acc = B24[j4];
                #pragma unroll
                for (int c = 0; c < 16; c++) FMA4(acc, u1s[c], W24[c*4+j4]);
                u2s[j4*4+0]=fmaxf(acc.x,0.f); u2s[j4*4+1]=fmaxf(acc.y,0.f);
                u2s[j4*4+2]=fmaxf(acc.z,0.f); u2s[j4*4+3]=fmaxf(acc.w,0.f);
            }
            float u3s[8];
            #pragma unroll
            for (int j2 = 0; j2 < 2; j2++){
                float4 acc = B34[j2];
                #pragma unroll
                for (int c = 0; c < 16; c++) FMA4(acc, u2s[c], W34[c*2+j2]);
                u3s[j2*4+0]=fmaxf(acc.x,0.f); u3s[j2*4+1]=fmaxf(acc.y,0.f);
                u3s[j2*4+2]=fmaxf(acc.z,0.f); u3s[j2*4+3]=fmaxf(acc.w,0.f);
            }
            float4 e4 = *(const float4*)(L + 632);
            #pragma unroll
            for (int c = 0; c < 8; c++) FMA4(e4, u3s[c], W44[c]);
            float mx = fmaxf(fmaxf(e4.x, e4.y), fmaxf(e4.z, e4.w));
            float ls = logf(expf(e4.x-mx)+expf(e4.y-mx)+expf(e4.z-mx)+expf(e4.w-mx)) + mx;
            float4 o;
            o.x = e4.x-ls; o.y = e4.y-ls; o.z = e4.z-ls; o.w = e4.w-ls;
            ((float4*)oute)[e] = o;
            float et = e4.x*sg2v[0] + e4.y*sg2v[1] + e4.z*sg2v[2] + e4.w*sg2v[3];
            etsum += et;
            float hs2 = xs.x*SD[0] + xs.y*SD[1] + xs.z*SD[2] + xs.w*SD[3] + SD[4];
            float hd2 = xd.x*SD[5] + xd.y*SD[6] + xd.z*SD[7] + xd.w*SD[8] + SD[9];
            sg[sp].y = lrelu(hs2 + hd2 + et);
        }
    }
    R[threadIdx.x] = etsum;
    __syncthreads();
    for (int off = 128; off > 0; off >>= 1){
        if (threadIdx.x < off) R[threadIdx.x] += R[threadIdx.x + off];
        __syncthreads();
    }
    if (threadIdx.x == 0) atomicAdd(&qw[3], R[0]);
}

// ---------- layer 2: single-pass online softmax, fused output ----------
__global__ void __launch_bounds__(256)
k_l2(const unsigned int* __restrict__ rowptr,
     const float2* __restrict__ sg, const float* __restrict__ xagg,
     const float2* __restrict__ h2t,
     const float* __restrict__ q, const float* __restrict__ b2,
     float* __restrict__ outn, float invE, int N)
{
    __shared__ float sq[64];
    if (threadIdx.x < 64) sq[threadIdx.x] = q[threadIdx.x];
    __syncthreads();
    int d = blockIdx.x*256 + threadIdx.x;
    if (d >= N) return;
    float c2 = sq[3] * invE;
    float4 xa = ((const float4*)xagg)[d];
    float h2d0 = xa.x*sq[28] + xa.y*sq[30] + xa.z*sq[32] + xa.w*sq[34] + sq[36];
    float h2d1 = xa.x*sq[29] + xa.y*sq[31] + xa.z*sq[33] + xa.w*sq[35] + sq[37];
    float hs2 = xa.x*sq[40] + xa.y*sq[41] + xa.z*sq[42] + xa.w*sq[43] + sq[44];
    float hd2 = xa.x*sq[45] + xa.y*sq[46] + xa.z*sq[47] + xa.w*sq[48] + sq[49];
    float aself = lrelu(hs2 + hd2 + c2);

    float mA = aself, zA = 1.f, a0A = h2d0, a1A = h2d1;
    float mB = -1e30f, zB = 0.f, a0B = 0.f, a1B = 0.f;

    unsigned int beg = rowptr[d], end = rowptr[d+1];
    unsigned int j = beg;
    for (; j + 1 < end; j += 2){
        float2 r0 = sg[j];
        float2 r1 = sg[j+1];
        int s0 = __float_as_int(r0.x);
        int s1 = __float_as_int(r1.x);
        float h00, h01, h10, h11;
        if (h2t){
            float2 hh0 = h2t[s0];
            float2 hh1 = h2t[s1];
            h00 = hh0.x; h01 = hh0.y; h10 = hh1.x; h11 = hh1.y;
        } else {
            float4 xs0 = ((const float4*)xagg)[s0];
            float4 xs1 = ((const float4*)xagg)[s1];
            h00 = xs0.x*sq[28] + xs0.y*sq[30] + xs0.z*sq[32] + xs0.w*sq[34] + sq[36];
            h01 = xs0.x*sq[29] + xs0.y*sq[31] + xs0.z*sq[33] + xs0.w*sq[35] + sq[37];
            h10 = xs1.x*sq[28] + xs1.y*sq[30] + xs1.z*sq[32] + xs1.w*sq[34] + sq[36];
            h11 = xs1.x*sq[29] + xs1.y*sq[31] + xs1.z*sq[33] + xs1.w*sq[35] + sq[37];
        }
        float mn0 = fmaxf(mA, r0.y);
        float sc0 = expf(mA - mn0);
        float p0  = expf(r0.y - mn0);
        zA  = zA*sc0 + p0;
        a0A = a0A*sc0 + p0*h00;
        a1A = a1A*sc0 + p0*h01;
        mA = mn0;
        float mn1 = fmaxf(mB, r1.y);
        float sc1 = expf(mB - mn1);
        float p1  = expf(r1.y - mn1);
        zB  = zB*sc1 + p1;
        a0B = a0B*sc1 + p1*h10;
        a1B = a1B*sc1 + p1*h11;
        mB = mn1;
    }
    if (j < end){
        float2 r0 = sg[j];
        int s0 = __float_as_int(r0.x);
        float h00, h01;
        if (h2t){
            float2 hh0 = h2t[s0];
            h00 = hh0.x; h01 = hh0.y;
        } else {
            float4 xs0 = ((const float4*)xagg)[s0];
            h00 = xs0.x*sq[28] + xs0.y*sq[30] + xs0.z*sq[32] + xs0.w*sq[34] + sq[36];
            h01 = xs0.x*sq[29] + xs0.y*sq[31] + xs0.z*sq[33] + xs0.w*sq[35] + sq[37];
        }
        float mn0 = fmaxf(mA, r0.y);
        float sc0 = expf(mA - mn0);
        float p0  = expf(r0.y - mn0);
        zA  = zA*sc0 + p0;
        a0A = a0A*sc0 + p0*h00;
        a1A = a1A*sc0 + p0*h01;
        mA = mn0;
    }
    float m = fmaxf(mA, mB);
    float sA = expf(mA - m), sB = expf(mB - m);
    float z = zA*sA + zB*sB;
    float inv = 1.0f / z;
    float v0 = (a0A*sA + a0B*sB)*inv + b2[0];
    float v1 = (a1A*sA + a1B*sB)*inv + b2[1];
    float mm = fmaxf(v0, v1);
    float ls = logf(expf(v0-mm) + expf(v1-mm)) + mm;
    float2 o;
    o.x = v0 - ls;
    o.y = v1 - ls;
    ((float2*)outn)[d] = o;
}

extern "C" void kernel_launch(void* const* d_in, const int* in_sizes, int n_in,
                              void* d_out, int out_size, void* d_ws, size_t ws_size,
                              hipStream_t stream)
{
    const float* x   = (const float*)d_in[0];
    const int*   ei  = (const int*)  d_in[1];
    const float* ea  = (const float*)d_in[2];
    const float* W1  = (const float*)d_in[3];
    const float* as1 = (const float*)d_in[4];
    const float* ad1 = (const float*)d_in[5];
    const float* We1 = (const float*)d_in[6];
    const float* ae1 = (const float*)d_in[7];
    const float* b1  = (const float*)d_in[8];
    const float* Wm1 = (const float*)d_in[9];
    const float* bm1 = (const float*)d_in[10];
    const float* Wm2 = (const float*)d_in[11];
    const float* bm2 = (const float*)d_in[12];
    const float* Wm3 = (const float*)d_in[13];
    const float* bm3 = (const float*)d_in[14];
    const float* Wm4 = (const float*)d_in[15];
    const float* bm4 = (const float*)d_in[16];
    const float* W2  = (const float*)d_in[17];
    const float* as2 = (const float*)d_in[18];
    const float* ad2 = (const float*)d_in[19];
    const float* We2 = (const float*)d_in[20];
    const float* ae2 = (const float*)d_in[21];
    const float* b2  = (const float*)d_in[22];

    const int N = in_sizes[0] / 4;
    const int E = in_sizes[1] / 2;

    int nb_n = (N + 255) / 256;
    int nb_e = (E + 255) / 256;
    int nb_e4 = (E + 1023) / 1024;
    if (nb_n > 1024) return;

    // common: q(256) | cnt(N u32) | rowptr(N+64 u32) | aux(1024 u32) | xagg(4N) | sg(2E)
    size_t commonFloats = 256 + (size_t)N + ((size_t)N + 64) + 1024 + 4*(size_t)N + 2*(size_t)E;
    // upgraded: + h2t(2N) + rank(E u16 -> E/2+16 floats)
    size_t upFloats = commonFloats + 2*(size_t)N + ((size_t)E/2 + 16);
    if (ws_size < commonFloats*sizeof(float)) return;
    bool up = (ws_size >= upFloats*sizeof(float));

    float* ws = (float*)d_ws;
    float* q  = ws;
    unsigned int* cnt    = (unsigned int*)(ws + 256);
    unsigned int* rowptr = cnt + N;
    unsigned int* aux    = rowptr + N + 64;
    float* xagg = (float*)(aux + 1024);
    float2* sg  = (float2*)(xagg + 4*(size_t)N);
    float2* h2t = nullptr;
    unsigned short* rank = nullptr;
    if (up){
        h2t  = (float2*)(sg + (size_t)E);
        rank = (unsigned short*)(h2t + (size_t)N);
    }

    float* outn = (float*)d_out;
    float* oute = outn + 2*(size_t)N;
    int* posStash = (int*)oute;   // fallback stash (each edge's own oute slot)

    // zero q + cnt
    hipMemsetAsync(d_ws, 0, (256 + (size_t)N)*sizeof(float), stream);

    float invE = 1.0f / (float)E;

    k_hist<<<256,256,0,stream>>>(ei, ea, q, cnt, rank, E);
    k_prep<<<1,64,0,stream>>>(W1, as1, ad1, We1, ae1, b1, Wm1, bm1,
                              W2, as2, ad2, We2, ae2, q, invE);
    k_scan1<<<nb_n,256,0,stream>>>(cnt, rowptr, aux, N);
    k_scan2<<<1,1024,0,stream>>>(aux, nb_n);
    k_scan3<<<nb_n,256,0,stream>>>(rowptr, cnt, aux, N, E);   // cnt becomes insert ptrs (fallback)
    k_scatter<<<nb_e,256,0,stream>>>(ei, ea, q, rowptr, rank, cnt, sg, posStash, E);
    k_l1<<<nb_n,256,0,stream>>>(rowptr, sg, x, q, xagg, h2t, N);
    k_mlp<<<nb_e4,256,0,stream>>>(ei, ea, xagg, Wm1, Wm2, bm2, Wm3, bm3,
                                  Wm4, bm4, q, q, sg, rowptr, rank, posStash, oute, E);
    k_l2<<<nb_n,256,0,stream>>>(rowptr, sg, xagg, h2t, q, b2, outn, invE, N);
}

// Round 23
// 554.256 us; speedup vs baseline: 1.9545x; 1.0198x over previous
//
#include <hip/hip_runtime.h>
#include <hip/hip_bf16.h>

static __device__ __forceinline__ float lrelu(float v){ return v >= 0.f ? v : 0.2f*v; }

#define FMA4(D_, S_, V_) { D_.x += (S_)*(V_).x; D_.y += (S_)*(V_).y; \
                           D_.z += (S_)*(V_).z; D_.w += (S_)*(V_).w; }

// q slots (256 floats):
// 0..2 sum(ea cols) | 3 sum(et2) | 4..6 g1 | 7 c1 | 8..11 g2
// 16..19 vs1 | 20..23 vd1 | 28..35 PM | 36..37 Q
// 40..43 S | 44 s0 | 45..48 D | 49 d0
// 64..127 A=W1@Wm1_top | 128..191 B=W1@Wm1_bot | 192..207 bb

// merged: ea column sums + dst histogram (+ optional rank record)
__global__ void __launch_bounds__(256)
k_hist(const int* __restrict__ ei, const float* __restrict__ ea,
       float* __restrict__ q, unsigned int* __restrict__ cnt,
       unsigned short* __restrict__ rank, int E)
{
    float s0 = 0.f, s1 = 0.f, s2 = 0.f;
    int stride = gridDim.x * blockDim.x;
    for (int e = blockIdx.x*blockDim.x + threadIdx.x; e < E; e += stride){
        size_t o = 3*(size_t)e;
        s0 += ea[o]; s1 += ea[o+1]; s2 += ea[o+2];
        unsigned int r = atomicAdd(&cnt[ei[E + e]], 1u);
        if (rank) rank[e] = (unsigned short)r;
    }
    for (int o = 32; o > 0; o >>= 1){
        s0 += __shfl_down(s0, o);
        s1 += __shfl_down(s1, o);
        s2 += __shfl_down(s2, o);
    }
    if ((threadIdx.x & 63) == 0){
        atomicAdd(&q[0], s0); atomicAdd(&q[1], s1); atomicAdd(&q[2], s2);
    }
}

__global__ void
k_prep(const float* __restrict__ W1, const float* __restrict__ as1,
       const float* __restrict__ ad1,
       const float* __restrict__ We1, const float* __restrict__ ae1,
       const float* __restrict__ b1,
       const float* __restrict__ Wm1, const float* __restrict__ bm1,
       const float* __restrict__ W2, const float* __restrict__ as2,
       const float* __restrict__ ad2,
       const float* __restrict__ We2, const float* __restrict__ ae2,
       float* __restrict__ q, float invE)
{
    __shared__ float sPM[8], sQ[2];
    int t = threadIdx.x;
    if (t < 16){
        int j = t;
        float a0=0,a1=0,a2=0,a3=0, c0=0,c1v=0,c2v=0,c3=0, tb=0;
        for (int i = 0; i < 16; i++){
            float wt = Wm1[i*16 + j];
            float wb = Wm1[(19+i)*16 + j];
            a0 += W1[0*16+i]*wt; a1 += W1[1*16+i]*wt;
            a2 += W1[2*16+i]*wt; a3 += W1[3*16+i]*wt;
            c0 += W1[0*16+i]*wb; c1v += W1[1*16+i]*wb;
            c2v += W1[2*16+i]*wb; c3 += W1[3*16+i]*wb;
            tb += b1[i]*(wt + wb);
        }
        q[64+0*16+j] = a0; q[64+1*16+j] = a1; q[64+2*16+j] = a2; q[64+3*16+j] = a3;
        q[128+0*16+j] = c0; q[128+1*16+j] = c1v; q[128+2*16+j] = c2v; q[128+3*16+j] = c3;
        q[192+j] = bm1[j] + tb;
    } else if (t < 20){
        int c = t - 16;
        float vs = 0.f, vd = 0.f, p0 = 0.f, p1 = 0.f;
        for (int i = 0; i < 16; i++){
            float w = W1[c*16 + i];
            vs += w * as1[i];
            vd += w * ad1[i];
            p0 += w * W2[i*2 + 0];
            p1 += w * W2[i*2 + 1];
        }
        q[16+c] = vs; q[20+c] = vd;
        q[28+c*2+0] = p0; q[28+c*2+1] = p1;
        sPM[c*2+0] = p0; sPM[c*2+1] = p1;
    } else if (t == 20){
        float c1 = 0.f;
        for (int k = 0; k < 3; k++){
            float g = 0.f;
            for (int j = 0; j < 16; j++) g += We1[k*16 + j] * ae1[j];
            q[4+k] = g;
            c1 += q[k] * invE * g;
        }
        q[7] = c1;
    } else if (t == 21){
        for (int k = 0; k < 4; k++)
            q[8+k] = We2[k*2] * ae2[0] + We2[k*2+1] * ae2[1];
    } else if (t == 22){
        float q0 = 0.f, q1 = 0.f;
        for (int i = 0; i < 16; i++){
            q0 += b1[i] * W2[i*2];
            q1 += b1[i] * W2[i*2+1];
        }
        q[36] = q0; q[37] = q1;
        sQ[0] = q0; sQ[1] = q1;
    }
    __syncthreads();
    if (t == 0){
        float a0 = as2[0], a1 = as2[1], d0 = ad2[0], d1 = ad2[1];
        for (int c = 0; c < 4; c++){
            q[40+c] = sPM[c*2]*a0 + sPM[c*2+1]*a1;
            q[45+c] = sPM[c*2]*d0 + sPM[c*2+1]*d1;
        }
        q[44] = sQ[0]*a0 + sQ[1]*a1;
        q[49] = sQ[0]*d0 + sQ[1]*d1;
    }
}

__global__ void __launch_bounds__(256)
k_scan1(const unsigned int* __restrict__ cnt, unsigned int* __restrict__ rowptr,
        unsigned int* __restrict__ aux, int N)
{
    __shared__ unsigned int s[256];
    int t = threadIdx.x;
    int i = blockIdx.x*256 + t;
    unsigned int v = (i < N) ? cnt[i] : 0u;
    s[t] = v;
    __syncthreads();
    for (int off = 1; off < 256; off <<= 1){
        unsigned int add = (t >= off) ? s[t-off] : 0u;
        __syncthreads();
        s[t] += add;
        __syncthreads();
    }
    if (i < N) rowptr[i] = s[t] - v;
    if (t == 255) aux[blockIdx.x] = s[t];
}

__global__ void __launch_bounds__(1024)
k_scan2(unsigned int* __restrict__ aux, int nbs)
{
    __shared__ unsigned int s[1024];
    int t = threadIdx.x;
    unsigned int v = (t < nbs) ? aux[t] : 0u;
    s[t] = v;
    __syncthreads();
    for (int off = 1; off < 1024; off <<= 1){
        unsigned int add = (t >= off) ? s[t-off] : 0u;
        __syncthreads();
        s[t] += add;
        __syncthreads();
    }
    if (t < nbs) aux[t] = s[t] - v;
}

__global__ void __launch_bounds__(256)
k_scan3(unsigned int* __restrict__ rowptr, unsigned int* __restrict__ ofs,
        const unsigned int* __restrict__ aux, int N, int E)
{
    int i = blockIdx.x*256 + threadIdx.x;
    if (i == 0) rowptr[N] = (unsigned int)E;
    if (i >= N) return;
    unsigned int r = rowptr[i] + aux[blockIdx.x];
    rowptr[i] = r;
    ofs[i] = r;   // insert pointers (used only by fallback atomic scatter)
}

__global__ void __launch_bounds__(256)
k_scatter(const int* __restrict__ ei, const float* __restrict__ ea,
          const float* __restrict__ q,
          const unsigned int* __restrict__ rowptr,
          const unsigned short* __restrict__ rank,
          unsigned int* __restrict__ ofs,
          float2* __restrict__ sg, int* __restrict__ posStash, int E)
{
    int e = blockIdx.x*256 + threadIdx.x;
    if (e >= E) return;
    int s = ei[e], d = ei[E + e];
    size_t o = 3*(size_t)e;
    float ge = ea[o]*q[4] + ea[o+1]*q[5] + ea[o+2]*q[6];
    unsigned int pos;
    if (rank){
        pos = rowptr[d] + (unsigned int)rank[e];
    } else {
        pos = atomicAdd(&ofs[d], 1u);
        posStash[4*(size_t)e] = (int)pos;
    }
    float2 r;
    r.x = __int_as_float(s);
    r.y = ge;
    sg[pos] = r;
}

// ---------- layer 1: gather, 2-way unrolled; optional h2 table ----------
__global__ void __launch_bounds__(256)
k_l1(const unsigned int* __restrict__ rowptr,
     const float2* __restrict__ sg, const float* __restrict__ x,
     const float* __restrict__ q, float* __restrict__ xagg,
     float2* __restrict__ h2t, int N)
{
    __shared__ float sq[64];
    if (threadIdx.x < 64) sq[threadIdx.x] = q[threadIdx.x];
    __syncthreads();
    int d = blockIdx.x*256 + threadIdx.x;
    if (d >= N) return;
    float4 xd = ((const float4*)x)[d];
    float hd = xd.x*sq[20] + xd.y*sq[21] + xd.z*sq[22] + xd.w*sq[23];
    float hs_self = xd.x*sq[16] + xd.y*sq[17] + xd.z*sq[18] + xd.w*sq[19];
    float p = expf(fminf(lrelu(hs_self + hd + sq[7]), 60.0f));
    float z0 = p, z1v = 0.f;
    float4 acc0, acc1;
    acc0.x = p*xd.x; acc0.y = p*xd.y; acc0.z = p*xd.z; acc0.w = p*xd.w;
    acc1.x = 0.f; acc1.y = 0.f; acc1.z = 0.f; acc1.w = 0.f;
    unsigned int beg = rowptr[d], end = rowptr[d+1];
    unsigned int j = beg;
    for (; j + 1 < end; j += 2){
        float2 r0 = sg[j];
        float2 r1 = sg[j+1];
        int s0 = __float_as_int(r0.x);
        int s1 = __float_as_int(r1.x);
        float4 xs0 = ((const float4*)x)[s0];
        float4 xs1 = ((const float4*)x)[s1];
        float av0 = xs0.x*sq[16] + xs0.y*sq[17] + xs0.z*sq[18] + xs0.w*sq[19] + hd + r0.y;
        float av1 = xs1.x*sq[16] + xs1.y*sq[17] + xs1.z*sq[18] + xs1.w*sq[19] + hd + r1.y;
        float pv0 = expf(fminf(lrelu(av0), 60.0f));
        float pv1 = expf(fminf(lrelu(av1), 60.0f));
        z0 += pv0; z1v += pv1;
        FMA4(acc0, pv0, xs0);
        FMA4(acc1, pv1, xs1);
    }
    if (j < end){
        float2 r0 = sg[j];
        int s0 = __float_as_int(r0.x);
        float4 xs0 = ((const float4*)x)[s0];
        float av0 = xs0.x*sq[16] + xs0.y*sq[17] + xs0.z*sq[18] + xs0.w*sq[19] + hd + r0.y;
        float pv0 = expf(fminf(lrelu(av0), 60.0f));
        z0 += pv0;
        FMA4(acc0, pv0, xs0);
    }
    float inv = 1.0f / (z0 + z1v);
    float4 acc;
    acc.x = (acc0.x + acc1.x) * inv;
    acc.y = (acc0.y + acc1.y) * inv;
    acc.z = (acc0.z + acc1.z) * inv;
    acc.w = (acc0.w + acc1.w) * inv;
    ((float4*)xagg)[d] = acc;
    if (h2t){
        float2 hh;
        hh.x = acc.x*sq[28] + acc.y*sq[30] + acc.z*sq[32] + acc.w*sq[34] + sq[36];
        hh.y = acc.x*sq[29] + acc.y*sq[31] + acc.z*sq[33] + acc.w*sq[35] + sq[37];
        h2t[d] = hh;
    }
}

// ---------- edge MLP: 4 edges per thread ----------
__global__ void __launch_bounds__(256)
k_mlp(const int* __restrict__ ei, const float* __restrict__ ea,
      const float* __restrict__ xagg,
      const float* __restrict__ Wm1, const float* __restrict__ Wm2,
      const float* __restrict__ bm2, const float* __restrict__ Wm3,
      const float* __restrict__ bm3, const float* __restrict__ Wm4,
      const float* __restrict__ bm4,
      const float* __restrict__ q, float* __restrict__ qw,
      float2* __restrict__ sg,
      const unsigned int* __restrict__ rowptr,
      const unsigned short* __restrict__ rank,
      const int* __restrict__ posStash,
      float* oute, int E)
{
    __shared__ __align__(16) float L[656];
    __shared__ float R[256];
    for (int t = threadIdx.x; t < 656; t += 256){
        float v;
        if      (t < 128)  v = q[64 + t];
        else if (t < 144)  v = q[192 + (t-128)];
        else if (t < 192)  v = Wm1[256 + (t-144)];
        else if (t < 448)  v = Wm2[t-192];
        else if (t < 464)  v = bm2[t-448];
        else if (t < 592)  v = Wm3[t-464];
        else if (t < 600)  v = bm3[t-592];
        else if (t < 632)  v = Wm4[t-600];
        else if (t < 636)  v = bm4[t-632];
        else if (t < 640)  v = q[8 + (t-636)];
        else               v = q[40 + (t-640)];
        L[t] = v;
    }
    __syncthreads();
    const float4* A4  = (const float4*)(L);
    const float4* B4  = (const float4*)(L + 64);
    const float4* bb4 = (const float4*)(L + 128);
    const float4* C34 = (const float4*)(L + 144);
    const float4* W24 = (const float4*)(L + 192);
    const float4* B24 = (const float4*)(L + 448);
    const float4* W34 = (const float4*)(L + 464);
    const float4* B34 = (const float4*)(L + 592);
    const float4* W44 = (const float4*)(L + 600);
    const float*  sg2v = L + 636;
    const float*  SD  = L + 640;

    int tg = blockIdx.x*256 + threadIdx.x;
    int e0 = tg*4;
    float etsum = 0.f;
    if (e0 + 3 < E){
        int4 sis = ((const int4*)ei)[tg];
        int4 dis = ((const int4*)(ei + E))[tg];
        int si[4] = { sis.x, sis.y, sis.z, sis.w };
        int di[4] = { dis.x, dis.y, dis.z, dis.w };
        float4 eA = ((const float4*)ea)[3*tg+0];
        float4 eB = ((const float4*)ea)[3*tg+1];
        float4 eC = ((const float4*)ea)[3*tg+2];
        float eaf[4][3] = {
            { eA.x, eA.y, eA.z },
            { eA.w, eB.x, eB.y },
            { eB.z, eB.w, eC.x },
            { eC.y, eC.z, eC.w }
        };
        int stash[4];
        if (rank){
            ushort4 rr = ((const ushort4*)rank)[tg];
            stash[0] = (int)(rowptr[di[0]] + rr.x);
            stash[1] = (int)(rowptr[di[1]] + rr.y);
            stash[2] = (int)(rowptr[di[2]] + rr.z);
            stash[3] = (int)(rowptr[di[3]] + rr.w);
        } else {
            #pragma unroll
            for (int k = 0; k < 4; k++)
                stash[k] = posStash[4*(size_t)(e0+k)];
        }

        float xsf[4][4], xdf[4][4], hsd[4];
        #pragma unroll
        for (int k = 0; k < 4; k++){
            float4 xs = ((const float4*)xagg)[si[k]];
            float4 xd = ((const float4*)xagg)[di[k]];
            xsf[k][0]=xs.x; xsf[k][1]=xs.y; xsf[k][2]=xs.z; xsf[k][3]=xs.w;
            xdf[k][0]=xd.x; xdf[k][1]=xd.y; xdf[k][2]=xd.z; xdf[k][3]=xd.w;
            float hs2 = xs.x*SD[0] + xs.y*SD[1] + xs.z*SD[2] + xs.w*SD[3] + SD[4];
            float hd2 = xd.x*SD[5] + xd.y*SD[6] + xd.z*SD[7] + xd.w*SD[8] + SD[9];
            hsd[k] = hs2 + hd2;
        }

        float u1[4][16];
        #pragma unroll
        for (int j4 = 0; j4 < 4; j4++){
            float4 acc0 = bb4[j4], acc1 = acc0, acc2 = acc0, acc3 = acc0;
            #pragma unroll
            for (int r = 0; r < 4; r++){
                float4 w = A4[r*4 + j4];
                FMA4(acc0, xsf[0][r], w); FMA4(acc1, xsf[1][r], w);
                FMA4(acc2, xsf[2][r], w); FMA4(acc3, xsf[3][r], w);
            }
            #pragma unroll
            for (int r = 0; r < 3; r++){
                float4 w = C34[r*4 + j4];
                FMA4(acc0, eaf[0][r], w); FMA4(acc1, eaf[1][r], w);
                FMA4(acc2, eaf[2][r], w); FMA4(acc3, eaf[3][r], w);
            }
            #pragma unroll
            for (int r = 0; r < 4; r++){
                float4 w = B4[r*4 + j4];
                FMA4(acc0, xdf[0][r], w); FMA4(acc1, xdf[1][r], w);
                FMA4(acc2, xdf[2][r], w); FMA4(acc3, xdf[3][r], w);
            }
            u1[0][j4*4+0]=fmaxf(acc0.x,0.f); u1[0][j4*4+1]=fmaxf(acc0.y,0.f);
            u1[0][j4*4+2]=fmaxf(acc0.z,0.f); u1[0][j4*4+3]=fmaxf(acc0.w,0.f);
            u1[1][j4*4+0]=fmaxf(acc1.x,0.f); u1[1][j4*4+1]=fmaxf(acc1.y,0.f);
            u1[1][j4*4+2]=fmaxf(acc1.z,0.f); u1[1][j4*4+3]=fmaxf(acc1.w,0.f);
            u1[2][j4*4+0]=fmaxf(acc2.x,0.f); u1[2][j4*4+1]=fmaxf(acc2.y,0.f);
            u1[2][j4*4+2]=fmaxf(acc2.z,0.f); u1[2][j4*4+3]=fmaxf(acc2.w,0.f);
            u1[3][j4*4+0]=fmaxf(acc3.x,0.f); u1[3][j4*4+1]=fmaxf(acc3.y,0.f);
            u1[3][j4*4+2]=fmaxf(acc3.z,0.f); u1[3][j4*4+3]=fmaxf(acc3.w,0.f);
        }

        float u2[4][16];
        #pragma unroll
        for (int j4 = 0; j4 < 4; j4++){
            float4 acc0 = B24[j4], acc1 = acc0, acc2 = acc0, acc3 = acc0;
            #pragma unroll
            for (int c = 0; c < 16; c++){
                float4 w = W24[c*4 + j4];
                FMA4(acc0, u1[0][c], w); FMA4(acc1, u1[1][c], w);
                FMA4(acc2, u1[2][c], w); FMA4(acc3, u1[3][c], w);
            }
            u2[0][j4*4+0]=fmaxf(acc0.x,0.f); u2[0][j4*4+1]=fmaxf(acc0.y,0.f);
            u2[0][j4*4+2]=fmaxf(acc0.z,0.f); u2[0][j4*4+3]=fmaxf(acc0.w,0.f);
            u2[1][j4*4+0]=fmaxf(acc1.x,0.f); u2[1][j4*4+1]=fmaxf(acc1.y,0.f);
            u2[1][j4*4+2]=fmaxf(acc1.z,0.f); u2[1][j4*4+3]=fmaxf(acc1.w,0.f);
            u2[2][j4*4+0]=fmaxf(acc2.x,0.f); u2[2][j4*4+1]=fmaxf(acc2.y,0.f);
            u2[2][j4*4+2]=fmaxf(acc2.z,0.f); u2[2][j4*4+3]=fmaxf(acc2.w,0.f);
            u2[3][j4*4+0]=fmaxf(acc3.x,0.f); u2[3][j4*4+1]=fmaxf(acc3.y,0.f);
            u2[3][j4*4+2]=fmaxf(acc3.z,0.f); u2[3][j4*4+3]=fmaxf(acc3.w,0.f);
        }

        float u3[4][8];
        #pragma unroll
        for (int j2 = 0; j2 < 2; j2++){
            float4 acc0 = B34[j2], acc1 = acc0, acc2 = acc0, acc3 = acc0;
            #pragma unroll
            for (int c = 0; c < 16; c++){
                float4 w = W34[c*2 + j2];
                FMA4(acc0, u2[0][c], w); FMA4(acc1, u2[1][c], w);
                FMA4(acc2, u2[2][c], w); FMA4(acc3, u2[3][c], w);
            }
            u3[0][j2*4+0]=fmaxf(acc0.x,0.f); u3[0][j2*4+1]=fmaxf(acc0.y,0.f);
            u3[0][j2*4+2]=fmaxf(acc0.z,0.f); u3[0][j2*4+3]=fmaxf(acc0.w,0.f);
            u3[1][j2*4+0]=fmaxf(acc1.x,0.f); u3[1][j2*4+1]=fmaxf(acc1.y,0.f);
            u3[1][j2*4+2]=fmaxf(acc1.z,0.f); u3[1][j2*4+3]=fmaxf(acc1.w,0.f);
            u3[2][j2*4+0]=fmaxf(acc2.x,0.f); u3[2][j2*4+1]=fmaxf(acc2.y,0.f);
            u3[2][j2*4+2]=fmaxf(acc2.z,0.f); u3[2][j2*4+3]=fmaxf(acc2.w,0.f);
            u3[3][j2*4+0]=fmaxf(acc3.x,0.f); u3[3][j2*4+1]=fmaxf(acc3.y,0.f);
            u3[3][j2*4+2]=fmaxf(acc3.z,0.f); u3[3][j2*4+3]=fmaxf(acc3.w,0.f);
        }

        float4 ev[4];
        {
            float4 b4v = *(const float4*)(L + 632);
            ev[0] = b4v; ev[1] = b4v; ev[2] = b4v; ev[3] = b4v;
            #pragma unroll
            for (int c = 0; c < 8; c++){
                float4 w = W44[c];
                FMA4(ev[0], u3[0][c], w); FMA4(ev[1], u3[1][c], w);
                FMA4(ev[2], u3[2][c], w); FMA4(ev[3], u3[3][c], w);
            }
        }

        #pragma unroll
        for (int k = 0; k < 4; k++){
            float4 e4 = ev[k];
            float mx = fmaxf(fmaxf(e4.x, e4.y), fmaxf(e4.z, e4.w));
            float ls = logf(expf(e4.x-mx)+expf(e4.y-mx)+expf(e4.z-mx)+expf(e4.w-mx)) + mx;
            float4 o;
            o.x = e4.x-ls; o.y = e4.y-ls; o.z = e4.z-ls; o.w = e4.w-ls;
            ((float4*)oute)[e0+k] = o;
            float et = e4.x*sg2v[0] + e4.y*sg2v[1] + e4.z*sg2v[2] + e4.w*sg2v[3];
            etsum += et;
            sg[stash[k]].y = lrelu(hsd[k] + et);
        }
    } else if (e0 < E){
        for (int e = e0; e < E; e++){
            int sp;
            if (rank) sp = (int)(rowptr[ei[E+e]] + rank[e]);
            else      sp = posStash[4*(size_t)e];
            int si = ei[e], di = ei[E+e];
            float4 xs = ((const float4*)xagg)[si];
            float4 xd = ((const float4*)xagg)[di];
            size_t eo = 3*(size_t)e;
            float e0v = ea[eo], e1v = ea[eo+1], e2v = ea[eo+2];
            float u1s[16];
            #pragma unroll
            for (int j4 = 0; j4 < 4; j4++){
                float4 acc = bb4[j4];
                FMA4(acc, xs.x, A4[0*4+j4]); FMA4(acc, xs.y, A4[1*4+j4]);
                FMA4(acc, xs.z, A4[2*4+j4]); FMA4(acc, xs.w, A4[3*4+j4]);
                FMA4(acc, e0v, C34[0*4+j4]); FMA4(acc, e1v, C34[1*4+j4]);
                FMA4(acc, e2v, C34[2*4+j4]);
                FMA4(acc, xd.x, B4[0*4+j4]); FMA4(acc, xd.y, B4[1*4+j4]);
                FMA4(acc, xd.z, B4[2*4+j4]); FMA4(acc, xd.w, B4[3*4+j4]);
                u1s[j4*4+0]=fmaxf(acc.x,0.f); u1s[j4*4+1]=fmaxf(acc.y,0.f);
                u1s[j4*4+2]=fmaxf(acc.z,0.f); u1s[j4*4+3]=fmaxf(acc.w,0.f);
            }
            float u2s[16];
            #pragma unroll
            for (int j4 = 0; j4 < 4; j4++){
                float4 acc = B24[j4];
                #pragma unroll
                for (int c = 0; c < 16; c++) FMA4(acc, u1s[c], W24[c*4+j4]);
                u2s[j4*4+0]=fmaxf(acc.x,0.f); u2s[j4*4+1]=fmaxf(acc.y,0.f);
                u2s[j4*4+2]=fmaxf(acc.z,0.f); u2s[j4*4+3]=fmaxf(acc.w,0.f);
            }
            float u3s[8];
            #pragma unroll
            for (int j2 = 0; j2 < 2; j2++){
                float4 acc = B34[j2];
                #pragma unroll
                for (int c = 0; c < 16; c++) FMA4(acc, u2s[c], W34[c*2+j2]);
                u3s[j2*4+0]=fmaxf(acc.x,0.f); u3s[j2*4+1]=fmaxf(acc.y,0.f);
                u3s[j2*4+2]=fmaxf(acc.z,0.f); u3s[j2*4+3]=fmaxf(acc.w,0.f);
            }
            float4 e4 = *(const float4*)(L + 632);
            #pragma unroll
            for (int c = 0; c < 8; c++) FMA4(e4, u3s[c], W44[c]);
            float mx = fmaxf(fmaxf(e4.x, e4.y), fmaxf(e4.z, e4.w));
            float ls = logf(expf(e4.x-mx)+expf(e4.y-mx)+expf(e4.z-mx)+expf(e4.w-mx)) + mx;
            float4 o;
            o.x = e4.x-ls; o.y = e4.y-ls; o.z = e4.z-ls; o.w = e4.w-ls;
            ((float4*)oute)[e] = o;
            float et = e4.x*sg2v[0] + e4.y*sg2v[1] + e4.z*sg2v[2] + e4.w*sg2v[3];
            etsum += et;
            float hs2 = xs.x*SD[0] + xs.y*SD[1] + xs.z*SD[2] + xs.w*SD[3] + SD[4];
            float hd2 = xd.x*SD[5] + xd.y*SD[6] + xd.z*SD[7] + xd.w*SD[8] + SD[9];
            sg[sp].y = lrelu(hs2 + hd2 + et);
        }
    }
    R[threadIdx.x] = etsum;
    __syncthreads();
    for (int off = 128; off > 0; off >>= 1){
        if (threadIdx.x < off) R[threadIdx.x] += R[threadIdx.x + off];
        __syncthreads();
    }
    if (threadIdx.x == 0) atomicAdd(&qw[3], R[0]);
}

// ---------- layer 2: single-pass online softmax, fused output ----------
__global__ void __launch_bounds__(256)
k_l2(const unsigned int* __restrict__ rowptr,
     const float2* __restrict__ sg, const float* __restrict__ xagg,
     const float2* __restrict__ h2t,
     const float* __restrict__ q, const float* __restrict__ b2,
     float* __restrict__ outn, float invE, int N)
{
    __shared__ float sq[64];
    if (threadIdx.x < 64) sq[threadIdx.x] = q[threadIdx.x];
    __syncthreads();
    int d = blockIdx.x*256 + threadIdx.x;
    if (d >= N) return;
    float c2 = sq[3] * invE;
    float4 xa = ((const float4*)xagg)[d];
    float h2d0 = xa.x*sq[28] + xa.y*sq[30] + xa.z*sq[32] + xa.w*sq[34] + sq[36];
    float h2d1 = xa.x*sq[29] + xa.y*sq[31] + xa.z*sq[33] + xa.w*sq[35] + sq[37];
    float hs2 = xa.x*sq[40] + xa.y*sq[41] + xa.z*sq[42] + xa.w*sq[43] + sq[44];
    float hd2 = xa.x*sq[45] + xa.y*sq[46] + xa.z*sq[47] + xa.w*sq[48] + sq[49];
    float aself = lrelu(hs2 + hd2 + c2);

    float mA = aself, zA = 1.f, a0A = h2d0, a1A = h2d1;
    float mB = -1e30f, zB = 0.f, a0B = 0.f, a1B = 0.f;

    unsigned int beg = rowptr[d], end = rowptr[d+1];
    unsigned int j = beg;
    for (; j + 1 < end; j += 2){
        float2 r0 = sg[j];
        float2 r1 = sg[j+1];
        int s0 = __float_as_int(r0.x);
        int s1 = __float_as_int(r1.x);
        float h00, h01, h10, h11;
        if (h2t){
            float2 hh0 = h2t[s0];
            float2 hh1 = h2t[s1];
            h00 = hh0.x; h01 = hh0.y; h10 = hh1.x; h11 = hh1.y;
        } else {
            float4 xs0 = ((const float4*)xagg)[s0];
            float4 xs1 = ((const float4*)xagg)[s1];
            h00 = xs0.x*sq[28] + xs0.y*sq[30] + xs0.z*sq[32] + xs0.w*sq[34] + sq[36];
            h01 = xs0.x*sq[29] + xs0.y*sq[31] + xs0.z*sq[33] + xs0.w*sq[35] + sq[37];
            h10 = xs1.x*sq[28] + xs1.y*sq[30] + xs1.z*sq[32] + xs1.w*sq[34] + sq[36];
            h11 = xs1.x*sq[29] + xs1.y*sq[31] + xs1.z*sq[33] + xs1.w*sq[35] + sq[37];
        }
        float mn0 = fmaxf(mA, r0.y);
        float sc0 = expf(mA - mn0);
        float p0  = expf(r0.y - mn0);
        zA  = zA*sc0 + p0;
        a0A = a0A*sc0 + p0*h00;
        a1A = a1A*sc0 + p0*h01;
        mA = mn0;
        float mn1 = fmaxf(mB, r1.y);
        float sc1 = expf(mB - mn1);
        float p1  = expf(r1.y - mn1);
        zB  = zB*sc1 + p1;
        a0B = a0B*sc1 + p1*h10;
        a1B = a1B*sc1 + p1*h11;
        mB = mn1;
    }
    if (j < end){
        float2 r0 = sg[j];
        int s0 = __float_as_int(r0.x);
        float h00, h01;
        if (h2t){
            float2 hh0 = h2t[s0];
            h00 = hh0.x; h01 = hh0.y;
        } else {
            float4 xs0 = ((const float4*)xagg)[s0];
            h00 = xs0.x*sq[28] + xs0.y*sq[30] + xs0.z*sq[32] + xs0.w*sq[34] + sq[36];
            h01 = xs0.x*sq[29] + xs0.y*sq[31] + xs0.z*sq[33] + xs0.w*sq[35] + sq[37];
        }
        float mn0 = fmaxf(mA, r0.y);
        float sc0 = expf(mA - mn0);
        float p0  = expf(r0.y - mn0);
        zA  = zA*sc0 + p0;
        a0A = a0A*sc0 + p0*h00;
        a1A = a1A*sc0 + p0*h01;
        mA = mn0;
    }
    float m = fmaxf(mA, mB);
    float sA = expf(mA - m), sB = expf(mB - m);
    float z = zA*sA + zB*sB;
    float inv = 1.0f / z;
    float v0 = (a0A*sA + a0B*sB)*inv + b2[0];
    float v1 = (a1A*sA + a1B*sB)*inv + b2[1];
    float mm = fmaxf(v0, v1);
    float ls = logf(expf(v0-mm) + expf(v1-mm)) + mm;
    float2 o;
    o.x = v0 - ls;
    o.y = v1 - ls;
    ((float2*)outn)[d] = o;
}

extern "C" void kernel_launch(void* const* d_in, const int* in_sizes, int n_in,
                              void* d_out, int out_size, void* d_ws, size_t ws_size,
                              hipStream_t stream)
{
    const float* x   = (const float*)d_in[0];
    const int*   ei  = (const int*)  d_in[1];
    const float* ea  = (const float*)d_in[2];
    const float* W1  = (const float*)d_in[3];
    const float* as1 = (const float*)d_in[4];
    const float* ad1 = (const float*)d_in[5];
    const float* We1 = (const float*)d_in[6];
    const float* ae1 = (const float*)d_in[7];
    const float* b1  = (const float*)d_in[8];
    const float* Wm1 = (const float*)d_in[9];
    const float* bm1 = (const float*)d_in[10];
    const float* Wm2 = (const float*)d_in[11];
    const float* bm2 = (const float*)d_in[12];
    const float* Wm3 = (const float*)d_in[13];
    const float* bm3 = (const float*)d_in[14];
    const float* Wm4 = (const float*)d_in[15];
    const float* bm4 = (const float*)d_in[16];
    const float* W2  = (const float*)d_in[17];
    const float* as2 = (const float*)d_in[18];
    const float* ad2 = (const float*)d_in[19];
    const float* We2 = (const float*)d_in[20];
    const float* ae2 = (const float*)d_in[21];
    const float* b2  = (const float*)d_in[22];

    const int N = in_sizes[0] / 4;
    const int E = in_sizes[1] / 2;

    int nb_n = (N + 255) / 256;
    int nb_e = (E + 255) / 256;
    int nb_e4 = (E + 1023) / 1024;
    if (nb_n > 1024) return;

    // common: q(256) | cnt(N u32) | rowptr(N+64 u32) | aux(1024 u32) | xagg(4N) | sg(2E)
    size_t commonFloats = 256 + (size_t)N + ((size_t)N + 64) + 1024 + 4*(size_t)N + 2*(size_t)E;
    // upgraded: + h2t(2N) + rank(E u16 -> E/2+16 floats)
    size_t upFloats = commonFloats + 2*(size_t)N + ((size_t)E/2 + 16);
    if (ws_size < commonFloats*sizeof(float)) return;
    bool up = (ws_size >= upFloats*sizeof(float));

    float* ws = (float*)d_ws;
    float* q  = ws;
    unsigned int* cnt    = (unsigned int*)(ws + 256);
    unsigned int* rowptr = cnt + N;
    unsigned int* aux    = rowptr + N + 64;
    float* xagg = (float*)(aux + 1024);
    float2* sg  = (float2*)(xagg + 4*(size_t)N);
    float2* h2t = nullptr;
    unsigned short* rank = nullptr;
    if (up){
        h2t  = (float2*)(sg + (size_t)E);
        rank = (unsigned short*)(h2t + (size_t)N);
    }

    float* outn = (float*)d_out;
    float* oute = outn + 2*(size_t)N;
    int* posStash = (int*)oute;   // fallback stash (each edge's own oute slot)

    // zero q + cnt
    hipMemsetAsync(d_ws, 0, (256 + (size_t)N)*sizeof(float), stream);

    float invE = 1.0f / (float)E;

    k_hist<<<128,256,0,stream>>>(ei, ea, q, cnt, rank, E);
    k_prep<<<1,64,0,stream>>>(W1, as1, ad1, We1, ae1, b1, Wm1, bm1,
                              W2, as2, ad2, We2, ae2, q, invE);
    k_scan1<<<nb_n,256,0,stream>>>(cnt, rowptr, aux, N);
    k_scan2<<<1,1024,0,stream>>>(aux, nb_n);
    k_scan3<<<nb_n,256,0,stream>>>(rowptr, cnt, aux, N, E);   // cnt becomes insert ptrs (fallback)
    k_scatter<<<nb_e,256,0,stream>>>(ei, ea, q, rowptr, rank, cnt, sg, posStash, E);
    k_l1<<<nb_n,256,0,stream>>>(rowptr, sg, x, q, xagg, h2t, N);
    k_mlp<<<nb_e4,256,0,stream>>>(ei, ea, xagg, Wm1, Wm2, bm2, Wm3, bm3,
                                  Wm4, bm4, q, q, sg, rowptr, rank, posStash, oute, E);
    k_l2<<<nb_n,256,0,stream>>>(rowptr, sg, xagg, h2t, q, b2, outn, invE, N);
}